// Round 13
// baseline (1645.841 us; speedup 1.0000x reference)
//
#include <hip/hip_runtime.h>
#include <hip/hip_bf16.h>
#include <math.h>

#define NN 4096
#define NE 16384
#define NLAYERS 4

__device__ __forceinline__ float gelu_f(float x) {
  return 0.5f * x * (1.0f + erff(x * 0.70710678118654752440f));
}

union F16U { float4 v4[4]; float f[16]; };

__global__ void k_init(const int* __restrict__ x, const float* __restrict__ atom_emb,
                       const float* __restrict__ edge_attr, const float* __restrict__ edge_w,
                       const float* __restrict__ edge_b, float* __restrict__ h,
                       float* __restrict__ ef, int* __restrict__ counts) {
  const int idx = blockIdx.x * 256 + threadIdx.x;      // 0..524287 (= NN*128 = NE*32)
  h[idx] = atom_emb[x[idx >> 7] * 128 + (idx & 127)];
  ef[idx] = edge_attr[idx >> 5] * edge_w[idx & 31] + edge_b[idx & 31];
  if (idx < NN) counts[idx] = 0;
}

__global__ void k_hist(const int* __restrict__ eidx, int* __restrict__ counts) {
  const int e = blockIdx.x * 256 + threadIdx.x;
  if (e < NE) atomicAdd(&counts[eidx[NE + e]], 1);
}

__global__ void k_scan(const int* __restrict__ counts, int* __restrict__ offs,
                       int* __restrict__ heads) {
  __shared__ int tmp[1024];
  const int t = threadIdx.x;
  const int c0 = counts[t*4], c1 = counts[t*4+1], c2 = counts[t*4+2], c3 = counts[t*4+3];
  const int s = c0 + c1 + c2 + c3;
  tmp[t] = s; __syncthreads();
  for (int off = 1; off < 1024; off <<= 1) {
    int v = (t >= off) ? tmp[t - off] : 0;
    __syncthreads();
    tmp[t] += v;
    __syncthreads();
  }
  int base = tmp[t] - s;
  offs[t*4]   = base;                heads[t*4]   = base;
  offs[t*4+1] = base + c0;           heads[t*4+1] = base + c0;
  offs[t*4+2] = base + c0 + c1;      heads[t*4+2] = base + c0 + c1;
  offs[t*4+3] = base + c0 + c1 + c2; heads[t*4+3] = base + c0 + c1 + c2;
  if (t == 1023) offs[NN] = tmp[1023];
}

__global__ void k_scatter(const int* __restrict__ eidx, int* __restrict__ heads,
                          int* __restrict__ elist) {
  const int e = blockIdx.x * 256 + threadIdx.x;
  if (e < NE) {
    int p = atomicAdd(&heads[eidx[NE + e]], 1);
    elist[p] = e;
  }
}

// C[N x NC] = act(A[N x 128] @ W[128 x NC] + bias); 256 thr, 32x64 tile
__global__ __launch_bounds__(256) void k_gemm(const float* __restrict__ A,
                                              const float* __restrict__ W,
                                              const float* __restrict__ bias,
                                              float* __restrict__ C, int NC, int gelu) {
  __shared__ float As[32][128];   // 16 KB
  __shared__ float Ws[128][64];   // 32 KB
  const int t = threadIdx.x;
  const int n0 = blockIdx.y * 32, c0 = blockIdx.x * 64;
  for (int i = t; i < 1024; i += 256) {
    const int r = i >> 5, c4 = (i & 31) << 2;
    *(float4*)&As[r][c4] = *(const float4*)&A[(size_t)(n0 + r) * 128 + c4];
  }
  for (int i = t; i < 2048; i += 256) {
    const int kk = i >> 4, c4 = (i & 15) << 2;
    *(float4*)&Ws[kk][c4] = *(const float4*)&W[(size_t)kk * NC + c0 + c4];
  }
  __syncthreads();
  const int tx = t & 63, ty = t >> 6;
  float acc[8] = {0.f,0.f,0.f,0.f,0.f,0.f,0.f,0.f};
  for (int kk = 0; kk < 128; kk += 4) {
    const float w0 = Ws[kk+0][tx];
    const float w1 = Ws[kk+1][tx];
    const float w2 = Ws[kk+2][tx];
    const float w3 = Ws[kk+3][tx];
    #pragma unroll
    for (int j = 0; j < 8; j++) {
      const float4 a = *(const float4*)&As[ty*8 + j][kk];
      acc[j] += a.x*w0 + a.y*w1 + a.z*w2 + a.w*w3;
    }
  }
  const float bb = bias[c0 + tx];
  #pragma unroll
  for (int j = 0; j < 8; j++) {
    float v = acc[j] + bb;
    if (gelu) v = gelu_f(v);
    C[(size_t)(n0 + ty*8 + j) * NC + c0 + tx] = v;
  }
}

// qe[n,h,c] = sum_d q[n,h*128+d] * we[c,h*128+d]; 8 nodes per block
__global__ __launch_bounds__(256) void k_qe(const float* __restrict__ q,
                                            const float* __restrict__ we_l,
                                            float* __restrict__ qe) {
  __shared__ float qs[8][1024];   // 32 KB
  const int t = threadIdx.x;
  const int n0 = blockIdx.x * 8;
  for (int i = t; i < 2048; i += 256) {
    const int nn = i >> 8, c4 = (i & 255) << 2;
    *(float4*)&qs[nn][c4] = *(const float4*)&q[(size_t)(n0 + nn) * 1024 + c4];
  }
  __syncthreads();
  const int hh = t >> 5, c = t & 31;
  const float* wp = we_l + (size_t)c * 1024 + hh * 128;
  float acc[8] = {0.f,0.f,0.f,0.f,0.f,0.f,0.f,0.f};
  for (int d8 = 0; d8 < 16; d8++) {
    const float4 wa = *(const float4*)&wp[d8 * 8];
    const float4 wb = *(const float4*)&wp[d8 * 8 + 4];
    #pragma unroll
    for (int nn = 0; nn < 8; nn++) {
      const float4 a0 = *(const float4*)&qs[nn][hh*128 + d8*8];
      const float4 a1 = *(const float4*)&qs[nn][hh*128 + d8*8 + 4];
      acc[nn] += a0.x*wa.x + a0.y*wa.y + a0.z*wa.z + a0.w*wa.w
               + a1.x*wb.x + a1.y*wb.y + a1.z*wb.z + a1.w*wb.w;
    }
  }
  #pragma unroll
  for (int nn = 0; nn < 8; nn++)
    qe[(size_t)(n0 + nn) * 256 + hh * 32 + c] = acc[nn];
}

// per-dst-node edge attention with online softmax; 1 wave per node.
// lane: hh = lane>>3 (head), s8 = lane&7 -> dims d0 = hh*128 + s8*16
__global__ __launch_bounds__(64) void k_edge(const float* __restrict__ qb,
                                             const float* __restrict__ kb,
                                             const float* __restrict__ vb,
                                             const float* __restrict__ qe,
                                             const float* __restrict__ ef,
                                             const int* __restrict__ offs,
                                             const int* __restrict__ elist,
                                             const int* __restrict__ eidx,
                                             float* __restrict__ accb,
                                             float* __restrict__ sbuf) {
  const int n = blockIdx.x;
  const int lane = threadIdx.x;
  const int hh = lane >> 3, s8 = lane & 7;
  const int d0 = hh * 128 + s8 * 16;
  F16U qv;
  {
    const float4* qp = (const float4*)(qb + (size_t)n * 1024 + d0);
    #pragma unroll
    for (int i = 0; i < 4; i++) qv.v4[i] = qp[i];
  }
  const float4 qe4 = *(const float4*)(qe + (size_t)n * 256 + hh * 32 + s8 * 4);
  float m = -INFINITY, z = 0.f;
  float acc[16];
  #pragma unroll
  for (int i = 0; i < 16; i++) acc[i] = 0.f;
  float sx = 0.f, sy = 0.f, sz = 0.f, sw = 0.f;
  const int e0 = offs[n], e1 = offs[n + 1];
  for (int tt = e0; tt < e1; tt++) {
    const int e = elist[tt];
    const int src = eidx[e];
    F16U kv;
    {
      const float4* kp = (const float4*)(kb + (size_t)src * 1024 + d0);
      #pragma unroll
      for (int i = 0; i < 4; i++) kv.v4[i] = kp[i];
    }
    const float4 ef4 = *(const float4*)(ef + (size_t)e * 32 + s8 * 4);
    float p = qe4.x*ef4.x + qe4.y*ef4.y + qe4.z*ef4.z + qe4.w*ef4.w;
    #pragma unroll
    for (int i = 0; i < 16; i++) p += qv.f[i] * kv.f[i];
    p += __shfl_xor(p, 1);
    p += __shfl_xor(p, 2);
    p += __shfl_xor(p, 4);
    const float logit = p * 0.08838834764831845f;   // 1/sqrt(128)
    const float mn = fmaxf(m, logit);
    const float f = expf(m - mn);
    const float w = expf(logit - mn);
    z = z * f + w;
    F16U vv;
    {
      const float4* vp = (const float4*)(vb + (size_t)src * 1024 + d0);
      #pragma unroll
      for (int i = 0; i < 4; i++) vv.v4[i] = vp[i];
    }
    #pragma unroll
    for (int i = 0; i < 16; i++) acc[i] = acc[i] * f + w * vv.f[i];
    sx = sx * f + w * ef4.x; sy = sy * f + w * ef4.y;
    sz = sz * f + w * ef4.z; sw = sw * f + w * ef4.w;
    m = mn;
  }
  const float inv = 1.f / (z + 1e-16f);
  F16U ov;
  #pragma unroll
  for (int i = 0; i < 16; i++) ov.f[i] = acc[i] * inv;
  float4* ap = (float4*)(accb + (size_t)n * 1024 + d0);
  #pragma unroll
  for (int i = 0; i < 4; i++) ap[i] = ov.v4[i];
  *(float4*)(sbuf + (size_t)n * 256 + hh * 32 + s8 * 4) =
      make_float4(sx * inv, sy * inv, sz * inv, sw * inv);
}

// head-mean (incl. s@we correction) + skip + residual + LN + gelu, in-place on h
__global__ __launch_bounds__(128) void k_post(float* __restrict__ h,
                                              const float* __restrict__ accb,
                                              const float* __restrict__ sbuf,
                                              const float* __restrict__ we_l,
                                              const float* __restrict__ wskip_l,
                                              const float* __restrict__ bskip_l,
                                              const float* __restrict__ lng,
                                              const float* __restrict__ lnb) {
  const int n = blockIdx.x, d = threadIdx.x;
  __shared__ float hs[128], ss[256], red[128], stat[2];
  hs[d] = h[(size_t)n * 128 + d];
  ss[d] = sbuf[(size_t)n * 256 + d];
  ss[128 + d] = sbuf[(size_t)n * 256 + 128 + d];
  __syncthreads();
  float aggm = 0.f;
  #pragma unroll
  for (int hh = 0; hh < 8; hh++) {
    float val = accb[(size_t)n * 1024 + hh * 128 + d];
    const float* wp = we_l + hh * 128 + d;
    const float* sp = &ss[hh * 32];
    #pragma unroll
    for (int c = 0; c < 32; c++) val += sp[c] * wp[(size_t)c * 1024];
    aggm += val;
  }
  aggm *= 0.125f;
  float sk = bskip_l[d];
  for (int c = 0; c < 128; c++) sk += hs[c] * wskip_l[c * 128 + d];
  const float out = aggm + sk + hs[d];
  red[d] = out; __syncthreads();
  for (int s2 = 64; s2 > 0; s2 >>= 1) { if (d < s2) red[d] += red[d + s2]; __syncthreads(); }
  if (d == 0) stat[0] = red[0] * (1.f / 128.f);
  __syncthreads();
  const float mean = stat[0];
  const float dev = out - mean;
  red[d] = dev * dev; __syncthreads();
  for (int s2 = 64; s2 > 0; s2 >>= 1) { if (d < s2) red[d] += red[d + s2]; __syncthreads(); }
  if (d == 0) stat[1] = red[0] * (1.f / 128.f);
  __syncthreads();
  const float var = stat[1];
  const float y = dev / sqrtf(var + 1e-5f) * lng[d] + lnb[d];
  h[(size_t)n * 128 + d] = gelu_f(y);
}

// dense MHA (B=8, 512 tokens, 8 heads, hd=16); 1 wave per 64 q-rows
__global__ __launch_bounds__(64) void k_attn2(const float* __restrict__ qkvm,
                                              float* __restrict__ ob) {
  __shared__ float ks[512][16];
  __shared__ float vs[512][16];
  const int bh = blockIdx.x >> 3, rt = blockIdx.x & 7;
  const int b = bh >> 3, hh = bh & 7;
  const int lane = threadIdx.x;
  for (int i = lane; i < 8192; i += 64) {
    const int j = i >> 4, dd = i & 15;
    const size_t base = (size_t)(b * 512 + j) * 384 + hh * 16 + dd;
    ks[j][dd] = qkvm[base + 128];
    vs[j][dd] = qkvm[base + 256];
  }
  __syncthreads();
  const int nq = b * 512 + rt * 64 + lane;
  F16U qv;
  {
    const float4* qp = (const float4*)(qkvm + (size_t)nq * 384 + hh * 16);
    #pragma unroll
    for (int i = 0; i < 4; i++) qv.v4[i] = qp[i];
  }
  float m = -INFINITY, z = 0.f;
  float acc[16];
  #pragma unroll
  for (int i = 0; i < 16; i++) acc[i] = 0.f;
  for (int j = 0; j < 512; j++) {
    F16U kv;
    {
      const float4* kp = (const float4*)ks[j];
      #pragma unroll
      for (int i = 0; i < 4; i++) kv.v4[i] = kp[i];
    }
    float s = 0.f;
    #pragma unroll
    for (int i = 0; i < 16; i++) s += qv.f[i] * kv.f[i];
    s *= 0.25f;                                 // 1/sqrt(16)
    const float mn = fmaxf(m, s);
    const float f = expf(m - mn);
    const float w = expf(s - mn);
    z = z * f + w;
    F16U vv;
    {
      const float4* vp = (const float4*)vs[j];
      #pragma unroll
      for (int i = 0; i < 4; i++) vv.v4[i] = vp[i];
    }
    #pragma unroll
    for (int i = 0; i < 16; i++) acc[i] = acc[i] * f + w * vv.f[i];
    m = mn;
  }
  const float inv = 1.f / z;
  F16U ov;
  #pragma unroll
  for (int i = 0; i < 16; i++) ov.f[i] = acc[i] * inv;
  float4* op = (float4*)(ob + (size_t)nq * 128 + hh * 16);
  #pragma unroll
  for (int i = 0; i < 4; i++) op[i] = ov.v4[i];
}

// out[N x 3] = y2[N x 64] @ w3 + b3 -- OUTPUT IS FLOAT32 (reference output dtype).
// Rounds 4-11 failed solely by writing bf16 here (f32 buffer read back as tiny
// garbage -> absmax == max|ref| fingerprint). Keep f32 stores.
__global__ void k_final(const float* __restrict__ y2, const float* __restrict__ w3,
                        const float* __restrict__ b3, float* __restrict__ out) {
  const int idx = blockIdx.x * 256 + threadIdx.x;
  if (idx >= NN * 3) return;
  const int n = idx / 3, j = idx % 3;
  float s = b3[j];
  const float* yp = y2 + (size_t)n * 64;
  #pragma unroll
  for (int c = 0; c < 64; c++) s += yp[c] * w3[c * 3 + j];
  out[idx] = s;
}

extern "C" void kernel_launch(void* const* d_in, const int* in_sizes, int n_in,
                              void* d_out, int out_size, void* d_ws, size_t ws_size,
                              hipStream_t stream) {
  const int*   x         = (const int*)d_in[0];
  const int*   eidx      = (const int*)d_in[1];
  const float* edge_attr = (const float*)d_in[2];
  const float* atom_emb  = (const float*)d_in[4];
  const float* edge_w    = (const float*)d_in[5];
  const float* edge_b    = (const float*)d_in[6];
  const float* wq        = (const float*)d_in[7];
  const float* bq        = (const float*)d_in[8];
  const float* wk        = (const float*)d_in[9];
  const float* bk        = (const float*)d_in[10];
  const float* wv        = (const float*)d_in[11];
  const float* bv        = (const float*)d_in[12];
  const float* we        = (const float*)d_in[13];
  const float* wskip     = (const float*)d_in[14];
  const float* bskip     = (const float*)d_in[15];
  const float* ln_g      = (const float*)d_in[16];
  const float* ln_b      = (const float*)d_in[17];
  const float* mha_in_w  = (const float*)d_in[18];
  const float* mha_in_b  = (const float*)d_in[19];
  const float* mha_out_w = (const float*)d_in[20];
  const float* mha_out_b = (const float*)d_in[21];
  const float* w1        = (const float*)d_in[22];
  const float* b1        = (const float*)d_in[23];
  const float* w2        = (const float*)d_in[24];
  const float* b2        = (const float*)d_in[25];
  const float* w3        = (const float*)d_in[26];
  const float* b3        = (const float*)d_in[27];

  float* ws   = (float*)d_ws;
  float* h    = ws;
  float* ef   = h + 524288;
  float* qb   = ef + 524288;
  float* kb   = qb + 4194304;
  float* vb   = kb + 4194304;
  float* qe   = vb + 4194304;
  float* accb = qe + 1048576;
  float* sbuf = accb + 4194304;
  float* qkvm = qb;                 // MHA-phase aliases (q/k/v dead by then)
  float* ob   = kb;
  float* mo   = kb + 524288;
  float* y1   = kb + 1048576;
  float* y2   = kb + 1572864;
  int* counts = (int*)(sbuf + 1048576);
  int* offs   = counts + 4100;
  int* heads  = offs + 4100;
  int* elist  = heads + 4100;

  k_init<<<2048, 256, 0, stream>>>(x, atom_emb, edge_attr, edge_w, edge_b, h, ef, counts);
  k_hist<<<64, 256, 0, stream>>>(eidx, counts);
  k_scan<<<1, 1024, 0, stream>>>(counts, offs, heads);
  k_scatter<<<64, 256, 0, stream>>>(eidx, heads, elist);

  for (int i = 0; i < NLAYERS; i++) {
    const float* wq_i  = wq + (size_t)i * 131072;
    const float* wk_i  = wk + (size_t)i * 131072;
    const float* wv_i  = wv + (size_t)i * 131072;
    const float* bq_i  = bq + (size_t)i * 1024;
    const float* bk_i  = bk + (size_t)i * 1024;
    const float* bv_i  = bv + (size_t)i * 1024;
    const float* we_i  = we + (size_t)i * 32768;
    const float* wsk_i = wskip + (size_t)i * 16384;
    const float* bsk_i = bskip + (size_t)i * 128;
    const float* g_i   = ln_g + (size_t)i * 128;
    const float* b_i   = ln_b + (size_t)i * 128;

    k_gemm<<<dim3(16, 128), 256, 0, stream>>>(h, wq_i, bq_i, qb, 1024, 0);
    k_gemm<<<dim3(16, 128), 256, 0, stream>>>(h, wk_i, bk_i, kb, 1024, 0);
    k_gemm<<<dim3(16, 128), 256, 0, stream>>>(h, wv_i, bv_i, vb, 1024, 0);
    k_qe<<<512, 256, 0, stream>>>(qb, we_i, qe);
    k_edge<<<4096, 64, 0, stream>>>(qb, kb, vb, qe, ef, offs, elist, eidx, accb, sbuf);
    k_post<<<4096, 128, 0, stream>>>(h, accb, sbuf, we_i, wsk_i, bsk_i, g_i, b_i);
  }

  k_gemm<<<dim3(6, 128), 256, 0, stream>>>(h, mha_in_w, mha_in_b, qkvm, 384, 0);
  k_attn2<<<512, 64, 0, stream>>>(qkvm, ob);
  k_gemm<<<dim3(2, 128), 256, 0, stream>>>(ob, mha_out_w, mha_out_b, mo, 128, 0);
  k_gemm<<<dim3(2, 128), 256, 0, stream>>>(mo, w1, b1, y1, 128, 1);
  k_gemm<<<dim3(1, 128), 256, 0, stream>>>(y1, w2, b2, y2, 64, 1);
  k_final<<<48, 256, 0, stream>>>(y2, w3, b3, (float*)d_out);
}

// Round 14
// 923.433 us; speedup vs baseline: 1.7823x; 1.7823x over previous
//
#include <hip/hip_runtime.h>
#include <hip/hip_bf16.h>
#include <math.h>

#define NN 4096
#define NE 16384
#define NLAYERS 4

__device__ __forceinline__ float gelu_f(float x) {
  return 0.5f * x * (1.0f + erff(x * 0.70710678118654752440f));
}

union F16U { float4 v4[4]; float f[16]; };

__global__ void k_init(const int* __restrict__ x, const float* __restrict__ atom_emb,
                       const float* __restrict__ edge_attr, const float* __restrict__ edge_w,
                       const float* __restrict__ edge_b, float* __restrict__ h,
                       float* __restrict__ ef, int* __restrict__ counts) {
  const int idx = blockIdx.x * 256 + threadIdx.x;      // 0..524287 (= NN*128 = NE*32)
  h[idx] = atom_emb[x[idx >> 7] * 128 + (idx & 127)];
  ef[idx] = edge_attr[idx >> 5] * edge_w[idx & 31] + edge_b[idx & 31];
  if (idx < NN) counts[idx] = 0;
}

__global__ void k_hist(const int* __restrict__ eidx, int* __restrict__ counts) {
  const int e = blockIdx.x * 256 + threadIdx.x;
  if (e < NE) atomicAdd(&counts[eidx[NE + e]], 1);
}

__global__ void k_scan(const int* __restrict__ counts, int* __restrict__ offs,
                       int* __restrict__ heads) {
  __shared__ int tmp[1024];
  const int t = threadIdx.x;
  const int c0 = counts[t*4], c1 = counts[t*4+1], c2 = counts[t*4+2], c3 = counts[t*4+3];
  const int s = c0 + c1 + c2 + c3;
  tmp[t] = s; __syncthreads();
  for (int off = 1; off < 1024; off <<= 1) {
    int v = (t >= off) ? tmp[t - off] : 0;
    __syncthreads();
    tmp[t] += v;
    __syncthreads();
  }
  int base = tmp[t] - s;
  offs[t*4]   = base;                heads[t*4]   = base;
  offs[t*4+1] = base + c0;           heads[t*4+1] = base + c0;
  offs[t*4+2] = base + c0 + c1;      heads[t*4+2] = base + c0 + c1;
  offs[t*4+3] = base + c0 + c1 + c2; heads[t*4+3] = base + c0 + c1 + c2;
  if (t == 1023) offs[NN] = tmp[1023];
}

__global__ void k_scatter(const int* __restrict__ eidx, int* __restrict__ heads,
                          int* __restrict__ elist) {
  const int e = blockIdx.x * 256 + threadIdx.x;
  if (e < NE) {
    int p = atomicAdd(&heads[eidx[NE + e]], 1);
    elist[p] = e;
  }
}

// C[N x NC] = act(A[N x 128] @ W[128 x NC] + bias); 256 thr, 32x64 tile
__global__ __launch_bounds__(256) void k_gemm(const float* __restrict__ A,
                                              const float* __restrict__ W,
                                              const float* __restrict__ bias,
                                              float* __restrict__ C, int NC, int gelu) {
  __shared__ float As[32][128];   // 16 KB
  __shared__ float Ws[128][64];   // 32 KB
  const int t = threadIdx.x;
  const int n0 = blockIdx.y * 32, c0 = blockIdx.x * 64;
  for (int i = t; i < 1024; i += 256) {
    const int r = i >> 5, c4 = (i & 31) << 2;
    *(float4*)&As[r][c4] = *(const float4*)&A[(size_t)(n0 + r) * 128 + c4];
  }
  for (int i = t; i < 2048; i += 256) {
    const int kk = i >> 4, c4 = (i & 15) << 2;
    *(float4*)&Ws[kk][c4] = *(const float4*)&W[(size_t)kk * NC + c0 + c4];
  }
  __syncthreads();
  const int tx = t & 63, ty = t >> 6;
  float acc[8] = {0.f,0.f,0.f,0.f,0.f,0.f,0.f,0.f};
  for (int kk = 0; kk < 128; kk += 4) {
    const float w0 = Ws[kk+0][tx];
    const float w1 = Ws[kk+1][tx];
    const float w2 = Ws[kk+2][tx];
    const float w3 = Ws[kk+3][tx];
    #pragma unroll
    for (int j = 0; j < 8; j++) {
      const float4 a = *(const float4*)&As[ty*8 + j][kk];
      acc[j] += a.x*w0 + a.y*w1 + a.z*w2 + a.w*w3;
    }
  }
  const float bb = bias[c0 + tx];
  #pragma unroll
  for (int j = 0; j < 8; j++) {
    float v = acc[j] + bb;
    if (gelu) v = gelu_f(v);
    C[(size_t)(n0 + ty*8 + j) * NC + c0 + tx] = v;
  }
}

// corr[n][d] = sum_{k<256} sbuf[n][k] * we[(k&31)*1024 + (k>>5)*128 + d]
// K=256 GEMM, 32 nodes x 64 cols per block, two 128-row W chunks.
__global__ __launch_bounds__(256) void k_corr(const float* __restrict__ sbuf,
                                              const float* __restrict__ we_l,
                                              float* __restrict__ corrb) {
  __shared__ float As[32][256];   // 32 KB
  __shared__ float Ws[128][64];   // 32 KB
  const int t = threadIdx.x;
  const int n0 = blockIdx.y * 32, c0 = blockIdx.x * 64;
  for (int i = t; i < 2048; i += 256) {            // As: 32 x 256
    const int r = i >> 6, c4 = (i & 63) << 2;
    *(float4*)&As[r][c4] = *(const float4*)&sbuf[(size_t)(n0 + r) * 256 + c4];
  }
  const int tx = t & 63, ty = t >> 6;
  float acc[8] = {0.f,0.f,0.f,0.f,0.f,0.f,0.f,0.f};
  for (int kc = 0; kc < 2; kc++) {
    __syncthreads();
    for (int i = t; i < 2048; i += 256) {          // Ws: 128 x 64 (chunk kc)
      const int kk = i >> 4, c4 = (i & 15) << 2;
      const int k = kc * 128 + kk;
      const int hh = k >> 5, c = k & 31;
      *(float4*)&Ws[kk][c4] = *(const float4*)&we_l[(size_t)c * 1024 + hh * 128 + c0 + c4];
    }
    __syncthreads();
    for (int kk = 0; kk < 128; kk += 4) {
      const float w0 = Ws[kk+0][tx];
      const float w1 = Ws[kk+1][tx];
      const float w2 = Ws[kk+2][tx];
      const float w3 = Ws[kk+3][tx];
      #pragma unroll
      for (int j = 0; j < 8; j++) {
        const float4 a = *(const float4*)&As[ty*8 + j][kc*128 + kk];
        acc[j] += a.x*w0 + a.y*w1 + a.z*w2 + a.w*w3;
      }
    }
  }
  #pragma unroll
  for (int j = 0; j < 8; j++)
    corrb[(size_t)(n0 + ty*8 + j) * 128 + c0 + tx] = acc[j];
}

// qe[n,h,c] = sum_d q[n,h*128+d] * we[c,h*128+d]; 8 nodes per block
__global__ __launch_bounds__(256) void k_qe(const float* __restrict__ q,
                                            const float* __restrict__ we_l,
                                            float* __restrict__ qe) {
  __shared__ float qs[8][1024];   // 32 KB
  const int t = threadIdx.x;
  const int n0 = blockIdx.x * 8;
  for (int i = t; i < 2048; i += 256) {
    const int nn = i >> 8, c4 = (i & 255) << 2;
    *(float4*)&qs[nn][c4] = *(const float4*)&q[(size_t)(n0 + nn) * 1024 + c4];
  }
  __syncthreads();
  const int hh = t >> 5, c = t & 31;
  const float* wp = we_l + (size_t)c * 1024 + hh * 128;
  float acc[8] = {0.f,0.f,0.f,0.f,0.f,0.f,0.f,0.f};
  for (int d8 = 0; d8 < 16; d8++) {
    const float4 wa = *(const float4*)&wp[d8 * 8];
    const float4 wb = *(const float4*)&wp[d8 * 8 + 4];
    #pragma unroll
    for (int nn = 0; nn < 8; nn++) {
      const float4 a0 = *(const float4*)&qs[nn][hh*128 + d8*8];
      const float4 a1 = *(const float4*)&qs[nn][hh*128 + d8*8 + 4];
      acc[nn] += a0.x*wa.x + a0.y*wa.y + a0.z*wa.z + a0.w*wa.w
               + a1.x*wb.x + a1.y*wb.y + a1.z*wb.z + a1.w*wb.w;
    }
  }
  #pragma unroll
  for (int nn = 0; nn < 8; nn++)
    qe[(size_t)(n0 + nn) * 256 + hh * 32 + c] = acc[nn];
}

// per-dst-node edge attention with online softmax; 1 wave per node.
// lane: hh = lane>>3 (head), s8 = lane&7 -> dims d0 = hh*128 + s8*16
// Head-mean of P.V reduced in-wave (shfl over lane bits 3..5) -> accm is N x 128.
__global__ __launch_bounds__(64) void k_edge(const float* __restrict__ qb,
                                             const float* __restrict__ kb,
                                             const float* __restrict__ vb,
                                             const float* __restrict__ qe,
                                             const float* __restrict__ ef,
                                             const int* __restrict__ offs,
                                             const int* __restrict__ elist,
                                             const int* __restrict__ eidx,
                                             float* __restrict__ accm,
                                             float* __restrict__ sbuf) {
  const int n = blockIdx.x;
  const int lane = threadIdx.x;
  const int hh = lane >> 3, s8 = lane & 7;
  const int d0 = hh * 128 + s8 * 16;
  F16U qv;
  {
    const float4* qp = (const float4*)(qb + (size_t)n * 1024 + d0);
    #pragma unroll
    for (int i = 0; i < 4; i++) qv.v4[i] = qp[i];
  }
  const float4 qe4 = *(const float4*)(qe + (size_t)n * 256 + hh * 32 + s8 * 4);
  float m = -INFINITY, z = 0.f;
  float acc[16];
  #pragma unroll
  for (int i = 0; i < 16; i++) acc[i] = 0.f;
  float sx = 0.f, sy = 0.f, sz = 0.f, sw = 0.f;
  const int e0 = offs[n], e1 = offs[n + 1];
  for (int tt = e0; tt < e1; tt++) {
    const int e = elist[tt];
    const int src = eidx[e];
    F16U kv;
    {
      const float4* kp = (const float4*)(kb + (size_t)src * 1024 + d0);
      #pragma unroll
      for (int i = 0; i < 4; i++) kv.v4[i] = kp[i];
    }
    const float4 ef4 = *(const float4*)(ef + (size_t)e * 32 + s8 * 4);
    float p = qe4.x*ef4.x + qe4.y*ef4.y + qe4.z*ef4.z + qe4.w*ef4.w;
    #pragma unroll
    for (int i = 0; i < 16; i++) p += qv.f[i] * kv.f[i];
    p += __shfl_xor(p, 1);
    p += __shfl_xor(p, 2);
    p += __shfl_xor(p, 4);
    const float logit = p * 0.08838834764831845f;   // 1/sqrt(128)
    const float mn = fmaxf(m, logit);
    const float f = expf(m - mn);
    const float w = expf(logit - mn);
    z = z * f + w;
    F16U vv;
    {
      const float4* vp = (const float4*)(vb + (size_t)src * 1024 + d0);
      #pragma unroll
      for (int i = 0; i < 4; i++) vv.v4[i] = vp[i];
    }
    #pragma unroll
    for (int i = 0; i < 16; i++) acc[i] = acc[i] * f + w * vv.f[i];
    sx = sx * f + w * ef4.x; sy = sy * f + w * ef4.y;
    sz = sz * f + w * ef4.z; sw = sw * f + w * ef4.w;
    m = mn;
  }
  const float inv = 1.f / (z + 1e-16f);
  *(float4*)(sbuf + (size_t)n * 256 + hh * 32 + s8 * 4) =
      make_float4(sx * inv, sy * inv, sz * inv, sw * inv);
  F16U ov;
  #pragma unroll
  for (int i = 0; i < 16; i++) ov.f[i] = acc[i] * inv;
  // heads live in lane bits 3..5 -> butterfly over masks 8,16,32 sums over heads
  #pragma unroll
  for (int mask = 8; mask <= 32; mask <<= 1)
    #pragma unroll
    for (int i = 0; i < 16; i++) ov.f[i] += __shfl_xor(ov.f[i], mask);
  if (hh == 0) {
    #pragma unroll
    for (int i = 0; i < 16; i++) ov.f[i] *= 0.125f;
    float4* ap = (float4*)(accm + (size_t)n * 128 + s8 * 16);
    #pragma unroll
    for (int i = 0; i < 4; i++) ap[i] = ov.v4[i];
  }
}

// out = LN(accm + 0.125*corr + skb + h) * g + b, then gelu; in-place on h.
// Pure elementwise loads + block reduction (the old k_post's serial GEMMs are
// now the tiled k_gemm/k_corr kernels; old k_post was 220us latency-bound).
__global__ __launch_bounds__(128) void k_post2(float* __restrict__ h,
                                               const float* __restrict__ accm,
                                               const float* __restrict__ corrb,
                                               const float* __restrict__ skb,
                                               const float* __restrict__ lng,
                                               const float* __restrict__ lnb) {
  const int n = blockIdx.x, d = threadIdx.x;
  __shared__ float red[128], stat[2];
  const size_t o = (size_t)n * 128 + d;
  const float out = accm[o] + 0.125f * corrb[o] + skb[o] + h[o];
  red[d] = out; __syncthreads();
  for (int s2 = 64; s2 > 0; s2 >>= 1) { if (d < s2) red[d] += red[d + s2]; __syncthreads(); }
  if (d == 0) stat[0] = red[0] * (1.f / 128.f);
  __syncthreads();
  const float mean = stat[0];
  const float dev = out - mean;
  red[d] = dev * dev; __syncthreads();
  for (int s2 = 64; s2 > 0; s2 >>= 1) { if (d < s2) red[d] += red[d + s2]; __syncthreads(); }
  if (d == 0) stat[1] = red[0] * (1.f / 128.f);
  __syncthreads();
  const float var = stat[1];
  const float y = dev / sqrtf(var + 1e-5f) * lng[d] + lnb[d];
  h[o] = gelu_f(y);
}

// dense MHA (B=8, 512 tokens, 8 heads, hd=16); 1 wave per 64 q-rows
__global__ __launch_bounds__(64) void k_attn2(const float* __restrict__ qkvm,
                                              float* __restrict__ ob) {
  __shared__ float ks[512][16];
  __shared__ float vs[512][16];
  const int bh = blockIdx.x >> 3, rt = blockIdx.x & 7;
  const int b = bh >> 3, hh = bh & 7;
  const int lane = threadIdx.x;
  for (int i = lane; i < 8192; i += 64) {
    const int j = i >> 4, dd = i & 15;
    const size_t base = (size_t)(b * 512 + j) * 384 + hh * 16 + dd;
    ks[j][dd] = qkvm[base + 128];
    vs[j][dd] = qkvm[base + 256];
  }
  __syncthreads();
  const int nq = b * 512 + rt * 64 + lane;
  F16U qv;
  {
    const float4* qp = (const float4*)(qkvm + (size_t)nq * 384 + hh * 16);
    #pragma unroll
    for (int i = 0; i < 4; i++) qv.v4[i] = qp[i];
  }
  float m = -INFINITY, z = 0.f;
  float acc[16];
  #pragma unroll
  for (int i = 0; i < 16; i++) acc[i] = 0.f;
  for (int j = 0; j < 512; j++) {
    F16U kv;
    {
      const float4* kp = (const float4*)ks[j];
      #pragma unroll
      for (int i = 0; i < 4; i++) kv.v4[i] = kp[i];
    }
    float s = 0.f;
    #pragma unroll
    for (int i = 0; i < 16; i++) s += qv.f[i] * kv.f[i];
    s *= 0.25f;                                 // 1/sqrt(16)
    const float mn = fmaxf(m, s);
    const float f = expf(m - mn);
    const float w = expf(s - mn);
    z = z * f + w;
    F16U vv;
    {
      const float4* vp = (const float4*)vs[j];
      #pragma unroll
      for (int i = 0; i < 4; i++) vv.v4[i] = vp[i];
    }
    #pragma unroll
    for (int i = 0; i < 16; i++) acc[i] = acc[i] * f + w * vv.f[i];
    m = mn;
  }
  const float inv = 1.f / z;
  F16U ov;
  #pragma unroll
  for (int i = 0; i < 16; i++) ov.f[i] = acc[i] * inv;
  float4* op = (float4*)(ob + (size_t)nq * 128 + hh * 16);
  #pragma unroll
  for (int i = 0; i < 4; i++) op[i] = ov.v4[i];
}

// out[N x 3] = y2[N x 64] @ w3 + b3 -- OUTPUT IS FLOAT32 (reference output dtype)
__global__ void k_final(const float* __restrict__ y2, const float* __restrict__ w3,
                        const float* __restrict__ b3, float* __restrict__ out) {
  const int idx = blockIdx.x * 256 + threadIdx.x;
  if (idx >= NN * 3) return;
  const int n = idx / 3, j = idx % 3;
  float s = b3[j];
  const float* yp = y2 + (size_t)n * 64;
  #pragma unroll
  for (int c = 0; c < 64; c++) s += yp[c] * w3[c * 3 + j];
  out[idx] = s;
}

extern "C" void kernel_launch(void* const* d_in, const int* in_sizes, int n_in,
                              void* d_out, int out_size, void* d_ws, size_t ws_size,
                              hipStream_t stream) {
  const int*   x         = (const int*)d_in[0];
  const int*   eidx      = (const int*)d_in[1];
  const float* edge_attr = (const float*)d_in[2];
  const float* atom_emb  = (const float*)d_in[4];
  const float* edge_w    = (const float*)d_in[5];
  const float* edge_b    = (const float*)d_in[6];
  const float* wq        = (const float*)d_in[7];
  const float* bq        = (const float*)d_in[8];
  const float* wk        = (const float*)d_in[9];
  const float* bk        = (const float*)d_in[10];
  const float* wv        = (const float*)d_in[11];
  const float* bv        = (const float*)d_in[12];
  const float* we        = (const float*)d_in[13];
  const float* wskip     = (const float*)d_in[14];
  const float* bskip     = (const float*)d_in[15];
  const float* ln_g      = (const float*)d_in[16];
  const float* ln_b      = (const float*)d_in[17];
  const float* mha_in_w  = (const float*)d_in[18];
  const float* mha_in_b  = (const float*)d_in[19];
  const float* mha_out_w = (const float*)d_in[20];
  const float* mha_out_b = (const float*)d_in[21];
  const float* w1        = (const float*)d_in[22];
  const float* b1        = (const float*)d_in[23];
  const float* w2        = (const float*)d_in[24];
  const float* b2        = (const float*)d_in[25];
  const float* w3        = (const float*)d_in[26];
  const float* b3        = (const float*)d_in[27];

  float* ws   = (float*)d_ws;
  float* h    = ws;
  float* ef   = h + 524288;
  float* qb   = ef + 524288;
  float* kb   = qb + 4194304;
  float* vb   = kb + 4194304;
  float* qe   = vb + 4194304;
  float* big  = qe + 1048576;       // old accb region (4194304), subdivided:
  float* accm = big;                //   524288
  float* corrb= big + 524288;       //   524288
  float* skb  = big + 1048576;      //   524288
  float* sbuf = big + 4194304;      // 1048576
  float* qkvm = qb;                 // MHA-phase aliases (q/k/v dead by then)
  float* ob   = kb;
  float* mo   = kb + 524288;
  float* y1   = kb + 1048576;
  float* y2   = kb + 1572864;
  int* counts = (int*)(sbuf + 1048576);
  int* offs   = counts + 4100;
  int* heads  = offs + 4100;
  int* elist  = heads + 4100;

  k_init<<<2048, 256, 0, stream>>>(x, atom_emb, edge_attr, edge_w, edge_b, h, ef, counts);
  k_hist<<<64, 256, 0, stream>>>(eidx, counts);
  k_scan<<<1, 1024, 0, stream>>>(counts, offs, heads);
  k_scatter<<<64, 256, 0, stream>>>(eidx, heads, elist);

  for (int i = 0; i < NLAYERS; i++) {
    const float* wq_i  = wq + (size_t)i * 131072;
    const float* wk_i  = wk + (size_t)i * 131072;
    const float* wv_i  = wv + (size_t)i * 131072;
    const float* bq_i  = bq + (size_t)i * 1024;
    const float* bk_i  = bk + (size_t)i * 1024;
    const float* bv_i  = bv + (size_t)i * 1024;
    const float* we_i  = we + (size_t)i * 32768;
    const float* wsk_i = wskip + (size_t)i * 16384;
    const float* bsk_i = bskip + (size_t)i * 128;
    const float* g_i   = ln_g + (size_t)i * 128;
    const float* b_i   = ln_b + (size_t)i * 128;

    k_gemm<<<dim3(16, 128), 256, 0, stream>>>(h, wq_i, bq_i, qb, 1024, 0);
    k_gemm<<<dim3(16, 128), 256, 0, stream>>>(h, wk_i, bk_i, kb, 1024, 0);
    k_gemm<<<dim3(16, 128), 256, 0, stream>>>(h, wv_i, bv_i, vb, 1024, 0);
    k_gemm<<<dim3(2, 128), 256, 0, stream>>>(h, wsk_i, bsk_i, skb, 128, 0);
    k_qe<<<512, 256, 0, stream>>>(qb, we_i, qe);
    k_edge<<<4096, 64, 0, stream>>>(qb, kb, vb, qe, ef, offs, elist, eidx, accm, sbuf);
    k_corr<<<dim3(2, 128), 256, 0, stream>>>(sbuf, we_i, corrb);
    k_post2<<<4096, 128, 0, stream>>>(h, accm, corrb, skb, g_i, b_i);
  }

  k_gemm<<<dim3(6, 128), 256, 0, stream>>>(h, mha_in_w, mha_in_b, qkvm, 384, 0);
  k_attn2<<<512, 64, 0, stream>>>(qkvm, ob);
  k_gemm<<<dim3(2, 128), 256, 0, stream>>>(ob, mha_out_w, mha_out_b, mo, 128, 0);
  k_gemm<<<dim3(2, 128), 256, 0, stream>>>(mo, w1, b1, y1, 128, 1);
  k_gemm<<<dim3(1, 128), 256, 0, stream>>>(y1, w2, b2, y2, 64, 1);
  k_final<<<48, 256, 0, stream>>>(y2, w3, b3, (float*)d_out);
}

// Round 15
// 783.236 us; speedup vs baseline: 2.1013x; 1.1790x over previous
//
#include <hip/hip_runtime.h>
#include <hip/hip_bf16.h>
#include <math.h>

#define NN 4096
#define NE 16384
#define NLAYERS 4

__device__ __forceinline__ float gelu_f(float x) {
  return 0.5f * x * (1.0f + erff(x * 0.70710678118654752440f));
}

union F16U { float4 v4[4]; float f[16]; };

__global__ void k_init(const int* __restrict__ x, const float* __restrict__ atom_emb,
                       const float* __restrict__ edge_attr, const float* __restrict__ edge_w,
                       const float* __restrict__ edge_b, float* __restrict__ h,
                       float* __restrict__ ef, int* __restrict__ counts) {
  const int idx = blockIdx.x * 256 + threadIdx.x;      // 0..524287 (= NN*128 = NE*32)
  h[idx] = atom_emb[x[idx >> 7] * 128 + (idx & 127)];
  ef[idx] = edge_attr[idx >> 5] * edge_w[idx & 31] + edge_b[idx & 31];
  if (idx < NN) counts[idx] = 0;
}

__global__ void k_hist(const int* __restrict__ eidx, int* __restrict__ counts) {
  const int e = blockIdx.x * 256 + threadIdx.x;
  if (e < NE) atomicAdd(&counts[eidx[NE + e]], 1);
}

__global__ void k_scan(const int* __restrict__ counts, int* __restrict__ offs,
                       int* __restrict__ heads) {
  __shared__ int tmp[1024];
  const int t = threadIdx.x;
  const int c0 = counts[t*4], c1 = counts[t*4+1], c2 = counts[t*4+2], c3 = counts[t*4+3];
  const int s = c0 + c1 + c2 + c3;
  tmp[t] = s; __syncthreads();
  for (int off = 1; off < 1024; off <<= 1) {
    int v = (t >= off) ? tmp[t - off] : 0;
    __syncthreads();
    tmp[t] += v;
    __syncthreads();
  }
  int base = tmp[t] - s;
  offs[t*4]   = base;                heads[t*4]   = base;
  offs[t*4+1] = base + c0;           heads[t*4+1] = base + c0;
  offs[t*4+2] = base + c0 + c1;      heads[t*4+2] = base + c0 + c1;
  offs[t*4+3] = base + c0 + c1 + c2; heads[t*4+3] = base + c0 + c1 + c2;
  if (t == 1023) offs[NN] = tmp[1023];
}

__global__ void k_scatter(const int* __restrict__ eidx, int* __restrict__ heads,
                          int* __restrict__ elist) {
  const int e = blockIdx.x * 256 + threadIdx.x;
  if (e < NE) {
    int p = atomicAdd(&heads[eidx[NE + e]], 1);
    elist[p] = e;
  }
}

// C[N x NC] = act(A[N x 128] @ W[128 x NC] + bias).
// 64x64 macro-tile, 256 thr, 4x4 register tile/thread, A staged k-major (+1 pad).
// Per k-step: 2 ds_read_b128 for 32 FLOP (0.5 B/FLOP) -> VALU-bound (old: 2.25).
__global__ __launch_bounds__(256) void k_gemm2(const float* __restrict__ A,
                                               const float* __restrict__ W,
                                               const float* __restrict__ bias,
                                               float* __restrict__ C, int NC, int gelu) {
  __shared__ float As[128][65];   // k-major, padded: 33.3 KB
  __shared__ float Ws[128][64];   // 32 KB
  const int t = threadIdx.x;
  const int n0 = blockIdx.y * 64, c0 = blockIdx.x * 64;
  for (int i = t; i < 2048; i += 256) {            // A: 64 rows x 128 k, transpose
    const int r = i & 63, k4 = (i >> 6) << 2;
    const float4 a = *(const float4*)&A[(size_t)(n0 + r) * 128 + k4];
    As[k4+0][r] = a.x; As[k4+1][r] = a.y; As[k4+2][r] = a.z; As[k4+3][r] = a.w;
  }
  for (int i = t; i < 2048; i += 256) {            // W: 128 k x 64 cols
    const int kk = i >> 4, c4 = (i & 15) << 2;
    *(float4*)&Ws[kk][c4] = *(const float4*)&W[(size_t)kk * NC + c0 + c4];
  }
  __syncthreads();
  const int tr = (t >> 4) << 2;    // 0,4,...,60
  const int tc = (t & 15) << 2;    // 0,4,...,60
  float acc[4][4];
  #pragma unroll
  for (int i = 0; i < 4; i++)
    #pragma unroll
    for (int j = 0; j < 4; j++) acc[i][j] = 0.f;
  #pragma unroll 8
  for (int k = 0; k < 128; k++) {
    const float4 av = *(const float4*)&As[k][tr];
    const float4 wv = *(const float4*)&Ws[k][tc];
    acc[0][0] += av.x*wv.x; acc[0][1] += av.x*wv.y; acc[0][2] += av.x*wv.z; acc[0][3] += av.x*wv.w;
    acc[1][0] += av.y*wv.x; acc[1][1] += av.y*wv.y; acc[1][2] += av.y*wv.z; acc[1][3] += av.y*wv.w;
    acc[2][0] += av.z*wv.x; acc[2][1] += av.z*wv.y; acc[2][2] += av.z*wv.z; acc[2][3] += av.z*wv.w;
    acc[3][0] += av.w*wv.x; acc[3][1] += av.w*wv.y; acc[3][2] += av.w*wv.z; acc[3][3] += av.w*wv.w;
  }
  const float4 bb = *(const float4*)&bias[c0 + tc];
  #pragma unroll
  for (int i = 0; i < 4; i++) {
    float4 v;
    v.x = acc[i][0] + bb.x; v.y = acc[i][1] + bb.y;
    v.z = acc[i][2] + bb.z; v.w = acc[i][3] + bb.w;
    if (gelu) { v.x = gelu_f(v.x); v.y = gelu_f(v.y); v.z = gelu_f(v.z); v.w = gelu_f(v.w); }
    *(float4*)&C[(size_t)(n0 + tr + i) * NC + c0 + tc] = v;
  }
}

// corr[n][d] = sum_{k<256} sbuf[n][k] * we[(k&31)*1024 + (k>>5)*128 + d]
__global__ __launch_bounds__(256) void k_corr(const float* __restrict__ sbuf,
                                              const float* __restrict__ we_l,
                                              float* __restrict__ corrb) {
  __shared__ float As[32][256];   // 32 KB
  __shared__ float Ws[128][64];   // 32 KB
  const int t = threadIdx.x;
  const int n0 = blockIdx.y * 32, c0 = blockIdx.x * 64;
  for (int i = t; i < 2048; i += 256) {            // As: 32 x 256
    const int r = i >> 6, c4 = (i & 63) << 2;
    *(float4*)&As[r][c4] = *(const float4*)&sbuf[(size_t)(n0 + r) * 256 + c4];
  }
  const int tx = t & 63, ty = t >> 6;
  float acc[8] = {0.f,0.f,0.f,0.f,0.f,0.f,0.f,0.f};
  for (int kc = 0; kc < 2; kc++) {
    __syncthreads();
    for (int i = t; i < 2048; i += 256) {          // Ws: 128 x 64 (chunk kc)
      const int kk = i >> 4, c4 = (i & 15) << 2;
      const int k = kc * 128 + kk;
      const int hh = k >> 5, c = k & 31;
      *(float4*)&Ws[kk][c4] = *(const float4*)&we_l[(size_t)c * 1024 + hh * 128 + c0 + c4];
    }
    __syncthreads();
    for (int kk = 0; kk < 128; kk += 4) {
      const float w0 = Ws[kk+0][tx];
      const float w1 = Ws[kk+1][tx];
      const float w2 = Ws[kk+2][tx];
      const float w3 = Ws[kk+3][tx];
      #pragma unroll
      for (int j = 0; j < 8; j++) {
        const float4 a = *(const float4*)&As[ty*8 + j][kc*128 + kk];
        acc[j] += a.x*w0 + a.y*w1 + a.z*w2 + a.w*w3;
      }
    }
  }
  #pragma unroll
  for (int j = 0; j < 8; j++)
    corrb[(size_t)(n0 + ty*8 + j) * 128 + c0 + tx] = acc[j];
}

// qe[n,h,c] = sum_d q[n,h*128+d] * we[c,h*128+d]; 8 nodes per block
__global__ __launch_bounds__(256) void k_qe(const float* __restrict__ q,
                                            const float* __restrict__ we_l,
                                            float* __restrict__ qe) {
  __shared__ float qs[8][1024];   // 32 KB
  const int t = threadIdx.x;
  const int n0 = blockIdx.x * 8;
  for (int i = t; i < 2048; i += 256) {
    const int nn = i >> 8, c4 = (i & 255) << 2;
    *(float4*)&qs[nn][c4] = *(const float4*)&q[(size_t)(n0 + nn) * 1024 + c4];
  }
  __syncthreads();
  const int hh = t >> 5, c = t & 31;
  const float* wp = we_l + (size_t)c * 1024 + hh * 128;
  float acc[8] = {0.f,0.f,0.f,0.f,0.f,0.f,0.f,0.f};
  for (int d8 = 0; d8 < 16; d8++) {
    const float4 wa = *(const float4*)&wp[d8 * 8];
    const float4 wb = *(const float4*)&wp[d8 * 8 + 4];
    #pragma unroll
    for (int nn = 0; nn < 8; nn++) {
      const float4 a0 = *(const float4*)&qs[nn][hh*128 + d8*8];
      const float4 a1 = *(const float4*)&qs[nn][hh*128 + d8*8 + 4];
      acc[nn] += a0.x*wa.x + a0.y*wa.y + a0.z*wa.z + a0.w*wa.w
               + a1.x*wb.x + a1.y*wb.y + a1.z*wb.z + a1.w*wb.w;
    }
  }
  #pragma unroll
  for (int nn = 0; nn < 8; nn++)
    qe[(size_t)(n0 + nn) * 256 + hh * 32 + c] = acc[nn];
}

// per-dst-node edge attention with online softmax; 1 wave per node.
__global__ __launch_bounds__(64) void k_edge(const float* __restrict__ qb,
                                             const float* __restrict__ kb,
                                             const float* __restrict__ vb,
                                             const float* __restrict__ qe,
                                             const float* __restrict__ ef,
                                             const int* __restrict__ offs,
                                             const int* __restrict__ elist,
                                             const int* __restrict__ eidx,
                                             float* __restrict__ accm,
                                             float* __restrict__ sbuf) {
  const int n = blockIdx.x;
  const int lane = threadIdx.x;
  const int hh = lane >> 3, s8 = lane & 7;
  const int d0 = hh * 128 + s8 * 16;
  F16U qv;
  {
    const float4* qp = (const float4*)(qb + (size_t)n * 1024 + d0);
    #pragma unroll
    for (int i = 0; i < 4; i++) qv.v4[i] = qp[i];
  }
  const float4 qe4 = *(const float4*)(qe + (size_t)n * 256 + hh * 32 + s8 * 4);
  float m = -INFINITY, z = 0.f;
  float acc[16];
  #pragma unroll
  for (int i = 0; i < 16; i++) acc[i] = 0.f;
  float sx = 0.f, sy = 0.f, sz = 0.f, sw = 0.f;
  const int e0 = offs[n], e1 = offs[n + 1];
  for (int tt = e0; tt < e1; tt++) {
    const int e = elist[tt];
    const int src = eidx[e];
    F16U kv;
    {
      const float4* kp = (const float4*)(kb + (size_t)src * 1024 + d0);
      #pragma unroll
      for (int i = 0; i < 4; i++) kv.v4[i] = kp[i];
    }
    const float4 ef4 = *(const float4*)(ef + (size_t)e * 32 + s8 * 4);
    float p = qe4.x*ef4.x + qe4.y*ef4.y + qe4.z*ef4.z + qe4.w*ef4.w;
    #pragma unroll
    for (int i = 0; i < 16; i++) p += qv.f[i] * kv.f[i];
    p += __shfl_xor(p, 1);
    p += __shfl_xor(p, 2);
    p += __shfl_xor(p, 4);
    const float logit = p * 0.08838834764831845f;   // 1/sqrt(128)
    const float mn = fmaxf(m, logit);
    const float f = expf(m - mn);
    const float w = expf(logit - mn);
    z = z * f + w;
    F16U vv;
    {
      const float4* vp = (const float4*)(vb + (size_t)src * 1024 + d0);
      #pragma unroll
      for (int i = 0; i < 4; i++) vv.v4[i] = vp[i];
    }
    #pragma unroll
    for (int i = 0; i < 16; i++) acc[i] = acc[i] * f + w * vv.f[i];
    sx = sx * f + w * ef4.x; sy = sy * f + w * ef4.y;
    sz = sz * f + w * ef4.z; sw = sw * f + w * ef4.w;
    m = mn;
  }
  const float inv = 1.f / (z + 1e-16f);
  *(float4*)(sbuf + (size_t)n * 256 + hh * 32 + s8 * 4) =
      make_float4(sx * inv, sy * inv, sz * inv, sw * inv);
  F16U ov;
  #pragma unroll
  for (int i = 0; i < 16; i++) ov.f[i] = acc[i] * inv;
  #pragma unroll
  for (int mask = 8; mask <= 32; mask <<= 1)
    #pragma unroll
    for (int i = 0; i < 16; i++) ov.f[i] += __shfl_xor(ov.f[i], mask);
  if (hh == 0) {
    #pragma unroll
    for (int i = 0; i < 16; i++) ov.f[i] *= 0.125f;
    float4* ap = (float4*)(accm + (size_t)n * 128 + s8 * 16);
    #pragma unroll
    for (int i = 0; i < 4; i++) ap[i] = ov.v4[i];
  }
}

// out = LN(accm + 0.125*corr + skb + h) * g + b, then gelu; in-place on h.
__global__ __launch_bounds__(128) void k_post2(float* __restrict__ h,
                                               const float* __restrict__ accm,
                                               const float* __restrict__ corrb,
                                               const float* __restrict__ skb,
                                               const float* __restrict__ lng,
                                               const float* __restrict__ lnb) {
  const int n = blockIdx.x, d = threadIdx.x;
  __shared__ float red[128], stat[2];
  const size_t o = (size_t)n * 128 + d;
  const float out = accm[o] + 0.125f * corrb[o] + skb[o] + h[o];
  red[d] = out; __syncthreads();
  for (int s2 = 64; s2 > 0; s2 >>= 1) { if (d < s2) red[d] += red[d + s2]; __syncthreads(); }
  if (d == 0) stat[0] = red[0] * (1.f / 128.f);
  __syncthreads();
  const float mean = stat[0];
  const float dev = out - mean;
  red[d] = dev * dev; __syncthreads();
  for (int s2 = 64; s2 > 0; s2 >>= 1) { if (d < s2) red[d] += red[d + s2]; __syncthreads(); }
  if (d == 0) stat[1] = red[0] * (1.f / 128.f);
  __syncthreads();
  const float var = stat[1];
  const float y = dev / sqrtf(var + 1e-5f) * lng[d] + lnb[d];
  h[o] = gelu_f(y);
}

// transpose k/v out of qkvm into [bh][512][16] contiguous
__global__ void k_qkvt(const float* __restrict__ qkvm, float* __restrict__ kt,
                       float* __restrict__ vt) {
  const int idx = blockIdx.x * 256 + threadIdx.x;   // 0..524287
  const int bh = idx >> 13, rest = idx & 8191;
  const int j = rest >> 4, d = rest & 15;
  const int b = bh >> 3, hh = bh & 7;
  const size_t src = (size_t)(b * 512 + j) * 384 + hh * 16 + d;
  kt[idx] = qkvm[src + 128];
  vt[idx] = qkvm[src + 256];
}

// flash-split dense MHA: grid (ks=4, qt=2, bh=64), 256 thr, 16 KB LDS (8 waves/CU).
// Each thread owns one q-row over a 128-key split; writes (m, z, acc16) partials.
__global__ __launch_bounds__(256) void k_attn2b(const float* __restrict__ qkvm,
                                                const float* __restrict__ kt,
                                                const float* __restrict__ vt,
                                                float* __restrict__ pm,
                                                float* __restrict__ pz,
                                                float* __restrict__ pacc) {
  __shared__ float ks2[128][16];
  __shared__ float vs2[128][16];
  const int ksp = blockIdx.x, qt = blockIdx.y, bh = blockIdx.z;
  const int b = bh >> 3, hh = bh & 7;
  const int t = threadIdx.x;
  const size_t kbase = ((size_t)bh * 512 + ksp * 128) * 16;
  for (int i = t; i < 512; i += 256) {
    const int j = i >> 2, d4 = (i & 3) << 2;
    *(float4*)&ks2[j][d4] = *(const float4*)&kt[kbase + (size_t)j * 16 + d4];
    *(float4*)&vs2[j][d4] = *(const float4*)&vt[kbase + (size_t)j * 16 + d4];
  }
  __syncthreads();
  const int qrow = qt * 256 + t;
  const int nq = b * 512 + qrow;
  F16U qv;
  {
    const float4* qp = (const float4*)(qkvm + (size_t)nq * 384 + hh * 16);
    #pragma unroll
    for (int i = 0; i < 4; i++) qv.v4[i] = qp[i];
  }
  float m = -INFINITY, z = 0.f;
  float acc[16];
  #pragma unroll
  for (int i = 0; i < 16; i++) acc[i] = 0.f;
  for (int j = 0; j < 128; j++) {
    F16U kv;
    {
      const float4* kp = (const float4*)ks2[j];
      #pragma unroll
      for (int i = 0; i < 4; i++) kv.v4[i] = kp[i];
    }
    float s = 0.f;
    #pragma unroll
    for (int i = 0; i < 16; i++) s += qv.f[i] * kv.f[i];
    s *= 0.25f;                                   // 1/sqrt(16)
    const float mn = fmaxf(m, s);
    const float f = expf(m - mn);
    const float w = expf(s - mn);
    z = z * f + w;
    F16U vv;
    {
      const float4* vp = (const float4*)vs2[j];
      #pragma unroll
      for (int i = 0; i < 4; i++) vv.v4[i] = vp[i];
    }
    #pragma unroll
    for (int i = 0; i < 16; i++) acc[i] = acc[i] * f + w * vv.f[i];
    m = mn;
  }
  const int p = (bh * 512 + qrow) * 4 + ksp;
  pm[p] = m; pz[p] = z;
  float4* pp = (float4*)&pacc[(size_t)p * 16];
  F16U ov;
  #pragma unroll
  for (int i = 0; i < 16; i++) ov.f[i] = acc[i];
  #pragma unroll
  for (int i = 0; i < 4; i++) pp[i] = ov.v4[i];
}

// merge the 4 key-splits (exact log-sum-exp) -> ob[n][128]
__global__ void k_amerge(const float* __restrict__ pm, const float* __restrict__ pz,
                         const float* __restrict__ pacc, float* __restrict__ ob) {
  const int idx = blockIdx.x * 256 + threadIdx.x;   // 0..32767
  if (idx >= 32768) return;
  const int bh = idx >> 9, qrow = idx & 511;
  const int b = bh >> 3, hh = bh & 7;
  const float m0 = pm[idx*4+0], m1 = pm[idx*4+1], m2 = pm[idx*4+2], m3 = pm[idx*4+3];
  const float ms = fmaxf(fmaxf(m0, m1), fmaxf(m2, m3));
  const float w0 = expf(m0 - ms), w1 = expf(m1 - ms);
  const float w2 = expf(m2 - ms), w3 = expf(m3 - ms);
  const float z = pz[idx*4+0]*w0 + pz[idx*4+1]*w1 + pz[idx*4+2]*w2 + pz[idx*4+3]*w3;
  const float inv = 1.f / z;
  const float* a0 = &pacc[(size_t)(idx*4+0) * 16];
  const float* a1 = &pacc[(size_t)(idx*4+1) * 16];
  const float* a2 = &pacc[(size_t)(idx*4+2) * 16];
  const float* a3 = &pacc[(size_t)(idx*4+3) * 16];
  float* op = &ob[(size_t)(b * 512 + qrow) * 128 + hh * 16];
  #pragma unroll
  for (int d = 0; d < 16; d++)
    op[d] = (a0[d]*w0 + a1[d]*w1 + a2[d]*w2 + a3[d]*w3) * inv;
}

// out[N x 3] = y2[N x 64] @ w3 + b3 -- OUTPUT IS FLOAT32
__global__ void k_final(const float* __restrict__ y2, const float* __restrict__ w3,
                        const float* __restrict__ b3, float* __restrict__ out) {
  const int idx = blockIdx.x * 256 + threadIdx.x;
  if (idx >= NN * 3) return;
  const int n = idx / 3, j = idx % 3;
  float s = b3[j];
  const float* yp = y2 + (size_t)n * 64;
  #pragma unroll
  for (int c = 0; c < 64; c++) s += yp[c] * w3[c * 3 + j];
  out[idx] = s;
}

extern "C" void kernel_launch(void* const* d_in, const int* in_sizes, int n_in,
                              void* d_out, int out_size, void* d_ws, size_t ws_size,
                              hipStream_t stream) {
  const int*   x         = (const int*)d_in[0];
  const int*   eidx      = (const int*)d_in[1];
  const float* edge_attr = (const float*)d_in[2];
  const float* atom_emb  = (const float*)d_in[4];
  const float* edge_w    = (const float*)d_in[5];
  const float* edge_b    = (const float*)d_in[6];
  const float* wq        = (const float*)d_in[7];
  const float* bq        = (const float*)d_in[8];
  const float* wk        = (const float*)d_in[9];
  const float* bk        = (const float*)d_in[10];
  const float* wv        = (const float*)d_in[11];
  const float* bv        = (const float*)d_in[12];
  const float* we        = (const float*)d_in[13];
  const float* wskip     = (const float*)d_in[14];
  const float* bskip     = (const float*)d_in[15];
  const float* ln_g      = (const float*)d_in[16];
  const float* ln_b      = (const float*)d_in[17];
  const float* mha_in_w  = (const float*)d_in[18];
  const float* mha_in_b  = (const float*)d_in[19];
  const float* mha_out_w = (const float*)d_in[20];
  const float* mha_out_b = (const float*)d_in[21];
  const float* w1        = (const float*)d_in[22];
  const float* b1        = (const float*)d_in[23];
  const float* w2        = (const float*)d_in[24];
  const float* b2        = (const float*)d_in[25];
  const float* w3        = (const float*)d_in[26];
  const float* b3        = (const float*)d_in[27];

  float* ws   = (float*)d_ws;
  float* h    = ws;
  float* ef   = h + 524288;
  float* qb   = ef + 524288;
  float* kb   = qb + 4194304;
  float* vb   = kb + 4194304;
  float* qe   = vb + 4194304;
  float* big  = qe + 1048576;       // 4194304, subdivided:
  float* accm = big;                //   524288
  float* corrb= big + 524288;       //   524288
  float* skb  = big + 1048576;      //   524288
  float* sbuf = big + 4194304;      // 1048576
  // MHA-phase aliases (layer q/k/v buffers dead by then)
  float* qkvm = qb;                 // N*384
  float* kt   = vb;                 // 64*512*16 = 524288
  float* vt   = vb + 524288;        // 524288
  float* pm   = vb + 1048576;       // 131072
  float* pz   = vb + 1179648;       // 131072
  float* pacc = vb + 1310720;       // 2097152
  float* ob   = kb;
  float* mo   = kb + 524288;
  float* y1   = kb + 1048576;
  float* y2   = kb + 1572864;
  int* counts = (int*)(sbuf + 1048576);
  int* offs   = counts + 4100;
  int* heads  = offs + 4100;
  int* elist  = heads + 4100;

  k_init<<<2048, 256, 0, stream>>>(x, atom_emb, edge_attr, edge_w, edge_b, h, ef, counts);
  k_hist<<<64, 256, 0, stream>>>(eidx, counts);
  k_scan<<<1, 1024, 0, stream>>>(counts, offs, heads);
  k_scatter<<<64, 256, 0, stream>>>(eidx, heads, elist);

  for (int i = 0; i < NLAYERS; i++) {
    const float* wq_i  = wq + (size_t)i * 131072;
    const float* wk_i  = wk + (size_t)i * 131072;
    const float* wv_i  = wv + (size_t)i * 131072;
    const float* bq_i  = bq + (size_t)i * 1024;
    const float* bk_i  = bk + (size_t)i * 1024;
    const float* bv_i  = bv + (size_t)i * 1024;
    const float* we_i  = we + (size_t)i * 32768;
    const float* wsk_i = wskip + (size_t)i * 16384;
    const float* bsk_i = bskip + (size_t)i * 128;
    const float* g_i   = ln_g + (size_t)i * 128;
    const float* b_i   = ln_b + (size_t)i * 128;

    k_gemm2<<<dim3(16, 64), 256, 0, stream>>>(h, wq_i, bq_i, qb, 1024, 0);
    k_gemm2<<<dim3(16, 64), 256, 0, stream>>>(h, wk_i, bk_i, kb, 1024, 0);
    k_gemm2<<<dim3(16, 64), 256, 0, stream>>>(h, wv_i, bv_i, vb, 1024, 0);
    k_gemm2<<<dim3(2, 64), 256, 0, stream>>>(h, wsk_i, bsk_i, skb, 128, 0);
    k_qe<<<512, 256, 0, stream>>>(qb, we_i, qe);
    k_edge<<<4096, 64, 0, stream>>>(qb, kb, vb, qe, ef, offs, elist, eidx, accm, sbuf);
    k_corr<<<dim3(2, 128), 256, 0, stream>>>(sbuf, we_i, corrb);
    k_post2<<<4096, 128, 0, stream>>>(h, accm, corrb, skb, g_i, b_i);
  }

  k_gemm2<<<dim3(6, 64), 256, 0, stream>>>(h, mha_in_w, mha_in_b, qkvm, 384, 0);
  k_qkvt<<<2048, 256, 0, stream>>>(qkvm, kt, vt);
  k_attn2b<<<dim3(4, 2, 64), 256, 0, stream>>>(qkvm, kt, vt, pm, pz, pacc);
  k_amerge<<<128, 256, 0, stream>>>(pm, pz, pacc, ob);
  k_gemm2<<<dim3(2, 64), 256, 0, stream>>>(ob, mha_out_w, mha_out_b, mo, 128, 0);
  k_gemm2<<<dim3(2, 64), 256, 0, stream>>>(mo, w1, b1, y1, 128, 1);
  k_gemm2<<<dim3(1, 64), 256, 0, stream>>>(y1, w2, b2, y2, 64, 1);
  k_final<<<48, 256, 0, stream>>>(y2, w3, b3, (float*)d_out);
}

// Round 16
// 735.283 us; speedup vs baseline: 2.2384x; 1.0652x over previous
//
#include <hip/hip_runtime.h>
#include <hip/hip_bf16.h>
#include <math.h>

#define NN 4096
#define NE 16384
#define NLAYERS 4

__device__ __forceinline__ float gelu_f(float x) {
  return 0.5f * x * (1.0f + erff(x * 0.70710678118654752440f));
}

union F16U { float4 v4[4]; float f[16]; };

__global__ void k_init(const int* __restrict__ x, const float* __restrict__ atom_emb,
                       const float* __restrict__ edge_attr, const float* __restrict__ edge_w,
                       const float* __restrict__ edge_b, float* __restrict__ h,
                       float* __restrict__ ef, int* __restrict__ counts) {
  const int idx = blockIdx.x * 256 + threadIdx.x;      // 0..524287 (= NN*128 = NE*32)
  h[idx] = atom_emb[x[idx >> 7] * 128 + (idx & 127)];
  ef[idx] = edge_attr[idx >> 5] * edge_w[idx & 31] + edge_b[idx & 31];
  if (idx < NN) counts[idx] = 0;
}

__global__ void k_hist(const int* __restrict__ eidx, int* __restrict__ counts) {
  const int e = blockIdx.x * 256 + threadIdx.x;
  if (e < NE) atomicAdd(&counts[eidx[NE + e]], 1);
}

__global__ void k_scan(const int* __restrict__ counts, int* __restrict__ offs,
                       int* __restrict__ heads) {
  __shared__ int tmp[1024];
  const int t = threadIdx.x;
  const int c0 = counts[t*4], c1 = counts[t*4+1], c2 = counts[t*4+2], c3 = counts[t*4+3];
  const int s = c0 + c1 + c2 + c3;
  tmp[t] = s; __syncthreads();
  for (int off = 1; off < 1024; off <<= 1) {
    int v = (t >= off) ? tmp[t - off] : 0;
    __syncthreads();
    tmp[t] += v;
    __syncthreads();
  }
  int base = tmp[t] - s;
  offs[t*4]   = base;                heads[t*4]   = base;
  offs[t*4+1] = base + c0;           heads[t*4+1] = base + c0;
  offs[t*4+2] = base + c0 + c1;      heads[t*4+2] = base + c0 + c1;
  offs[t*4+3] = base + c0 + c1 + c2; heads[t*4+3] = base + c0 + c1 + c2;
  if (t == 1023) offs[NN] = tmp[1023];
}

__global__ void k_scatter(const int* __restrict__ eidx, int* __restrict__ heads,
                          int* __restrict__ elist) {
  const int e = blockIdx.x * 256 + threadIdx.x;
  if (e < NE) {
    int p = atomicAdd(&heads[eidx[NE + e]], 1);
    elist[p] = e;
  }
}

// generic GEMM: C[N x NC] = act(A[N x 128] @ W[128 x NC] + bias)
// 64x64 macro-tile, 256 thr, 4x4 register tile/thread, A staged k-major (padded).
__global__ __launch_bounds__(256) void k_gemm2(const float* __restrict__ A,
                                               const float* __restrict__ W,
                                               const float* __restrict__ bias,
                                               float* __restrict__ C, int NC, int gelu) {
  __shared__ float As[128][65];
  __shared__ float Ws[128][64];
  const int t = threadIdx.x;
  const int n0 = blockIdx.y * 64, c0 = blockIdx.x * 64;
  for (int i = t; i < 2048; i += 256) {
    const int r = i & 63, k4 = (i >> 6) << 2;
    const float4 a = *(const float4*)&A[(size_t)(n0 + r) * 128 + k4];
    As[k4+0][r] = a.x; As[k4+1][r] = a.y; As[k4+2][r] = a.z; As[k4+3][r] = a.w;
  }
  for (int i = t; i < 2048; i += 256) {
    const int kk = i >> 4, c4 = (i & 15) << 2;
    *(float4*)&Ws[kk][c4] = *(const float4*)&W[(size_t)kk * NC + c0 + c4];
  }
  __syncthreads();
  const int tr = (t >> 4) << 2;
  const int tc = (t & 15) << 2;
  float acc[4][4];
  #pragma unroll
  for (int i = 0; i < 4; i++)
    #pragma unroll
    for (int j = 0; j < 4; j++) acc[i][j] = 0.f;
  #pragma unroll 8
  for (int k = 0; k < 128; k++) {
    const float4 av = *(const float4*)&As[k][tr];
    const float4 wv = *(const float4*)&Ws[k][tc];
    acc[0][0] += av.x*wv.x; acc[0][1] += av.x*wv.y; acc[0][2] += av.x*wv.z; acc[0][3] += av.x*wv.w;
    acc[1][0] += av.y*wv.x; acc[1][1] += av.y*wv.y; acc[1][2] += av.y*wv.z; acc[1][3] += av.y*wv.w;
    acc[2][0] += av.z*wv.x; acc[2][1] += av.z*wv.y; acc[2][2] += av.z*wv.z; acc[2][3] += av.z*wv.w;
    acc[3][0] += av.w*wv.x; acc[3][1] += av.w*wv.y; acc[3][2] += av.w*wv.z; acc[3][3] += av.w*wv.w;
  }
  const float4 bb = *(const float4*)&bias[c0 + tc];
  #pragma unroll
  for (int i = 0; i < 4; i++) {
    float4 v;
    v.x = acc[i][0] + bb.x; v.y = acc[i][1] + bb.y;
    v.z = acc[i][2] + bb.z; v.w = acc[i][3] + bb.w;
    if (gelu) { v.x = gelu_f(v.x); v.y = gelu_f(v.y); v.z = gelu_f(v.z); v.w = gelu_f(v.w); }
    *(float4*)&C[(size_t)(n0 + tr + i) * NC + c0 + tc] = v;
  }
}

// fused per-layer q/k/v/skip GEMMs: z = 0/1/2 -> 1024-col q/k/v, z = 3 -> 128-col skip
__global__ __launch_bounds__(256) void k_gemmqkv(const float* __restrict__ A,
    const float* __restrict__ wq, const float* __restrict__ wk,
    const float* __restrict__ wv, const float* __restrict__ wsk,
    const float* __restrict__ bq, const float* __restrict__ bk,
    const float* __restrict__ bv, const float* __restrict__ bsk,
    float* __restrict__ qb, float* __restrict__ kb,
    float* __restrict__ vb, float* __restrict__ skb) {
  const int z = blockIdx.z;
  const float* W; const float* bias; float* C; int NC;
  if (z == 0)      { W = wq;  bias = bq;  C = qb;  NC = 1024; }
  else if (z == 1) { W = wk;  bias = bk;  C = kb;  NC = 1024; }
  else if (z == 2) { W = wv;  bias = bv;  C = vb;  NC = 1024; }
  else             { W = wsk; bias = bsk; C = skb; NC = 128;  }
  const int c0 = blockIdx.x * 64;
  if (c0 >= NC) return;                  // block-uniform early exit (skip slice)
  __shared__ float As[128][65];
  __shared__ float Ws[128][64];
  const int t = threadIdx.x;
  const int n0 = blockIdx.y * 64;
  for (int i = t; i < 2048; i += 256) {
    const int r = i & 63, k4 = (i >> 6) << 2;
    const float4 a = *(const float4*)&A[(size_t)(n0 + r) * 128 + k4];
    As[k4+0][r] = a.x; As[k4+1][r] = a.y; As[k4+2][r] = a.z; As[k4+3][r] = a.w;
  }
  for (int i = t; i < 2048; i += 256) {
    const int kk = i >> 4, c4 = (i & 15) << 2;
    *(float4*)&Ws[kk][c4] = *(const float4*)&W[(size_t)kk * NC + c0 + c4];
  }
  __syncthreads();
  const int tr = (t >> 4) << 2;
  const int tc = (t & 15) << 2;
  float acc[4][4];
  #pragma unroll
  for (int i = 0; i < 4; i++)
    #pragma unroll
    for (int j = 0; j < 4; j++) acc[i][j] = 0.f;
  #pragma unroll 8
  for (int k = 0; k < 128; k++) {
    const float4 av = *(const float4*)&As[k][tr];
    const float4 wv4 = *(const float4*)&Ws[k][tc];
    acc[0][0] += av.x*wv4.x; acc[0][1] += av.x*wv4.y; acc[0][2] += av.x*wv4.z; acc[0][3] += av.x*wv4.w;
    acc[1][0] += av.y*wv4.x; acc[1][1] += av.y*wv4.y; acc[1][2] += av.y*wv4.z; acc[1][3] += av.y*wv4.w;
    acc[2][0] += av.z*wv4.x; acc[2][1] += av.z*wv4.y; acc[2][2] += av.z*wv4.z; acc[2][3] += av.z*wv4.w;
    acc[3][0] += av.w*wv4.x; acc[3][1] += av.w*wv4.y; acc[3][2] += av.w*wv4.z; acc[3][3] += av.w*wv4.w;
  }
  const float4 bb = *(const float4*)&bias[c0 + tc];
  #pragma unroll
  for (int i = 0; i < 4; i++) {
    float4 v;
    v.x = acc[i][0] + bb.x; v.y = acc[i][1] + bb.y;
    v.z = acc[i][2] + bb.z; v.w = acc[i][3] + bb.w;
    *(float4*)&C[(size_t)(n0 + tr + i) * NC + c0 + tc] = v;
  }
}

// corr[n][d] = sum_{k<256} sbuf[n][k] * we[(k&31)*1024 + (k>>5)*128 + d]
__global__ __launch_bounds__(256) void k_corr(const float* __restrict__ sbuf,
                                              const float* __restrict__ we_l,
                                              float* __restrict__ corrb) {
  __shared__ float As[32][256];
  __shared__ float Ws[128][64];
  const int t = threadIdx.x;
  const int n0 = blockIdx.y * 32, c0 = blockIdx.x * 64;
  for (int i = t; i < 2048; i += 256) {
    const int r = i >> 6, c4 = (i & 63) << 2;
    *(float4*)&As[r][c4] = *(const float4*)&sbuf[(size_t)(n0 + r) * 256 + c4];
  }
  const int tx = t & 63, ty = t >> 6;
  float acc[8] = {0.f,0.f,0.f,0.f,0.f,0.f,0.f,0.f};
  for (int kc = 0; kc < 2; kc++) {
    __syncthreads();
    for (int i = t; i < 2048; i += 256) {
      const int kk = i >> 4, c4 = (i & 15) << 2;
      const int k = kc * 128 + kk;
      const int hh = k >> 5, c = k & 31;
      *(float4*)&Ws[kk][c4] = *(const float4*)&we_l[(size_t)c * 1024 + hh * 128 + c0 + c4];
    }
    __syncthreads();
    for (int kk = 0; kk < 128; kk += 4) {
      const float w0 = Ws[kk+0][tx];
      const float w1 = Ws[kk+1][tx];
      const float w2 = Ws[kk+2][tx];
      const float w3 = Ws[kk+3][tx];
      #pragma unroll
      for (int j = 0; j < 8; j++) {
        const float4 a = *(const float4*)&As[ty*8 + j][kc*128 + kk];
        acc[j] += a.x*w0 + a.y*w1 + a.z*w2 + a.w*w3;
      }
    }
  }
  #pragma unroll
  for (int j = 0; j < 8; j++)
    corrb[(size_t)(n0 + ty*8 + j) * 128 + c0 + tx] = acc[j];
}

// qe[n,h,c] = sum_d q[n,h*128+d] * we[c,h*128+d]; 8 nodes per block
__global__ __launch_bounds__(256) void k_qe(const float* __restrict__ q,
                                            const float* __restrict__ we_l,
                                            float* __restrict__ qe) {
  __shared__ float qs[8][1024];
  const int t = threadIdx.x;
  const int n0 = blockIdx.x * 8;
  for (int i = t; i < 2048; i += 256) {
    const int nn = i >> 8, c4 = (i & 255) << 2;
    *(float4*)&qs[nn][c4] = *(const float4*)&q[(size_t)(n0 + nn) * 1024 + c4];
  }
  __syncthreads();
  const int hh = t >> 5, c = t & 31;
  const float* wp = we_l + (size_t)c * 1024 + hh * 128;
  float acc[8] = {0.f,0.f,0.f,0.f,0.f,0.f,0.f,0.f};
  for (int d8 = 0; d8 < 16; d8++) {
    const float4 wa = *(const float4*)&wp[d8 * 8];
    const float4 wb = *(const float4*)&wp[d8 * 8 + 4];
    #pragma unroll
    for (int nn = 0; nn < 8; nn++) {
      const float4 a0 = *(const float4*)&qs[nn][hh*128 + d8*8];
      const float4 a1 = *(const float4*)&qs[nn][hh*128 + d8*8 + 4];
      acc[nn] += a0.x*wa.x + a0.y*wa.y + a0.z*wa.z + a0.w*wa.w
               + a1.x*wb.x + a1.y*wb.y + a1.z*wb.z + a1.w*wb.w;
    }
  }
  #pragma unroll
  for (int nn = 0; nn < 8; nn++)
    qe[(size_t)(n0 + nn) * 256 + hh * 32 + c] = acc[nn];
}

// per-dst-node edge attention with online softmax; 1 wave per node.
// Dot uses 4 independent partial chains to cut fp dependency latency.
__global__ __launch_bounds__(64) void k_edge(const float* __restrict__ qb,
                                             const float* __restrict__ kb,
                                             const float* __restrict__ vb,
                                             const float* __restrict__ qe,
                                             const float* __restrict__ ef,
                                             const int* __restrict__ offs,
                                             const int* __restrict__ elist,
                                             const int* __restrict__ eidx,
                                             float* __restrict__ accm,
                                             float* __restrict__ sbuf) {
  const int n = blockIdx.x;
  const int lane = threadIdx.x;
  const int hh = lane >> 3, s8 = lane & 7;
  const int d0 = hh * 128 + s8 * 16;
  F16U qv;
  {
    const float4* qp = (const float4*)(qb + (size_t)n * 1024 + d0);
    #pragma unroll
    for (int i = 0; i < 4; i++) qv.v4[i] = qp[i];
  }
  const float4 qe4 = *(const float4*)(qe + (size_t)n * 256 + hh * 32 + s8 * 4);
  float m = -INFINITY, z = 0.f;
  float acc[16];
  #pragma unroll
  for (int i = 0; i < 16; i++) acc[i] = 0.f;
  float sx = 0.f, sy = 0.f, sz = 0.f, sw = 0.f;
  const int e0 = offs[n], e1 = offs[n + 1];
  for (int tt = e0; tt < e1; tt++) {
    const int e = elist[tt];
    const int src = eidx[e];
    F16U kv;
    {
      const float4* kp = (const float4*)(kb + (size_t)src * 1024 + d0);
      #pragma unroll
      for (int i = 0; i < 4; i++) kv.v4[i] = kp[i];
    }
    const float4 ef4 = *(const float4*)(ef + (size_t)e * 32 + s8 * 4);
    float p0 = qe4.x*ef4.x + qe4.y*ef4.y;
    float p1 = qe4.z*ef4.z + qe4.w*ef4.w;
    float p2 = 0.f, p3 = 0.f;
    #pragma unroll
    for (int i = 0; i < 4; i++) {
      p0 += qv.f[i]      * kv.f[i];
      p1 += qv.f[4 + i]  * kv.f[4 + i];
      p2 += qv.f[8 + i]  * kv.f[8 + i];
      p3 += qv.f[12 + i] * kv.f[12 + i];
    }
    float p = (p0 + p1) + (p2 + p3);
    p += __shfl_xor(p, 1);
    p += __shfl_xor(p, 2);
    p += __shfl_xor(p, 4);
    const float logit = p * 0.08838834764831845f;   // 1/sqrt(128)
    const float mn = fmaxf(m, logit);
    const float f = expf(m - mn);
    const float w = expf(logit - mn);
    z = z * f + w;
    F16U vv;
    {
      const float4* vp = (const float4*)(vb + (size_t)src * 1024 + d0);
      #pragma unroll
      for (int i = 0; i < 4; i++) vv.v4[i] = vp[i];
    }
    #pragma unroll
    for (int i = 0; i < 16; i++) acc[i] = acc[i] * f + w * vv.f[i];
    sx = sx * f + w * ef4.x; sy = sy * f + w * ef4.y;
    sz = sz * f + w * ef4.z; sw = sw * f + w * ef4.w;
    m = mn;
  }
  const float inv = 1.f / (z + 1e-16f);
  *(float4*)(sbuf + (size_t)n * 256 + hh * 32 + s8 * 4) =
      make_float4(sx * inv, sy * inv, sz * inv, sw * inv);
  F16U ov;
  #pragma unroll
  for (int i = 0; i < 16; i++) ov.f[i] = acc[i] * inv;
  #pragma unroll
  for (int mask = 8; mask <= 32; mask <<= 1)
    #pragma unroll
    for (int i = 0; i < 16; i++) ov.f[i] += __shfl_xor(ov.f[i], mask);
  if (hh == 0) {
    #pragma unroll
    for (int i = 0; i < 16; i++) ov.f[i] *= 0.125f;
    float4* ap = (float4*)(accm + (size_t)n * 128 + s8 * 16);
    #pragma unroll
    for (int i = 0; i < 4; i++) ap[i] = ov.v4[i];
  }
}

// out = LN(accm + 0.125*corr + skb + h) * g + b, then gelu; in-place on h.
__global__ __launch_bounds__(128) void k_post2(float* __restrict__ h,
                                               const float* __restrict__ accm,
                                               const float* __restrict__ corrb,
                                               const float* __restrict__ skb,
                                               const float* __restrict__ lng,
                                               const float* __restrict__ lnb) {
  const int n = blockIdx.x, d = threadIdx.x;
  __shared__ float red[128], stat[2];
  const size_t o = (size_t)n * 128 + d;
  const float out = accm[o] + 0.125f * corrb[o] + skb[o] + h[o];
  red[d] = out; __syncthreads();
  for (int s2 = 64; s2 > 0; s2 >>= 1) { if (d < s2) red[d] += red[d + s2]; __syncthreads(); }
  if (d == 0) stat[0] = red[0] * (1.f / 128.f);
  __syncthreads();
  const float mean = stat[0];
  const float dev = out - mean;
  red[d] = dev * dev; __syncthreads();
  for (int s2 = 64; s2 > 0; s2 >>= 1) { if (d < s2) red[d] += red[d + s2]; __syncthreads(); }
  if (d == 0) stat[1] = red[0] * (1.f / 128.f);
  __syncthreads();
  const float var = stat[1];
  const float y = dev / sqrtf(var + 1e-5f) * lng[d] + lnb[d];
  h[o] = gelu_f(y);
}

// transpose k/v out of qkvm into [bh][512][16] contiguous
__global__ void k_qkvt(const float* __restrict__ qkvm, float* __restrict__ kt,
                       float* __restrict__ vt) {
  const int idx = blockIdx.x * 256 + threadIdx.x;   // 0..524287
  const int bh = idx >> 13, rest = idx & 8191;
  const int j = rest >> 4, d = rest & 15;
  const int b = bh >> 3, hh = bh & 7;
  const size_t src = (size_t)(b * 512 + j) * 384 + hh * 16 + d;
  kt[idx] = qkvm[src + 128];
  vt[idx] = qkvm[src + 256];
}

// flash-split dense MHA: grid (ks=4, qt=2, bh=64), 256 thr, 16 KB LDS.
// 2 keys/iter with combined rescale; dots split into 4 independent chains.
__global__ __launch_bounds__(256) void k_attn2b(const float* __restrict__ qkvm,
                                                const float* __restrict__ kt,
                                                const float* __restrict__ vt,
                                                float* __restrict__ pm,
                                                float* __restrict__ pz,
                                                float* __restrict__ pacc) {
  __shared__ float ks2[128][16];
  __shared__ float vs2[128][16];
  const int ksp = blockIdx.x, qt = blockIdx.y, bh = blockIdx.z;
  const int b = bh >> 3, hh = bh & 7;
  const int t = threadIdx.x;
  const size_t kbase = ((size_t)bh * 512 + ksp * 128) * 16;
  for (int i = t; i < 512; i += 256) {
    const int j = i >> 2, d4 = (i & 3) << 2;
    *(float4*)&ks2[j][d4] = *(const float4*)&kt[kbase + (size_t)j * 16 + d4];
    *(float4*)&vs2[j][d4] = *(const float4*)&vt[kbase + (size_t)j * 16 + d4];
  }
  __syncthreads();
  const int qrow = qt * 256 + t;
  const int nq = b * 512 + qrow;
  F16U qv;
  {
    const float4* qp = (const float4*)(qkvm + (size_t)nq * 384 + hh * 16);
    #pragma unroll
    for (int i = 0; i < 4; i++) qv.v4[i] = qp[i];
  }
  float m = -INFINITY, z = 0.f;
  float acc[16];
  #pragma unroll
  for (int i = 0; i < 16; i++) acc[i] = 0.f;
  for (int j = 0; j < 128; j += 2) {
    F16U k0, k1, v0, v1;
    {
      const float4* p0 = (const float4*)ks2[j];
      const float4* p1 = (const float4*)ks2[j + 1];
      const float4* q0 = (const float4*)vs2[j];
      const float4* q1 = (const float4*)vs2[j + 1];
      #pragma unroll
      for (int i = 0; i < 4; i++) {
        k0.v4[i] = p0[i]; k1.v4[i] = p1[i];
        v0.v4[i] = q0[i]; v1.v4[i] = q1[i];
      }
    }
    float a0 = 0.f, a1 = 0.f, a2 = 0.f, a3 = 0.f;
    float b0 = 0.f, b1 = 0.f, b2 = 0.f, b3 = 0.f;
    #pragma unroll
    for (int i = 0; i < 4; i++) {
      a0 += qv.f[i]      * k0.f[i];
      a1 += qv.f[4 + i]  * k0.f[4 + i];
      a2 += qv.f[8 + i]  * k0.f[8 + i];
      a3 += qv.f[12 + i] * k0.f[12 + i];
      b0 += qv.f[i]      * k1.f[i];
      b1 += qv.f[4 + i]  * k1.f[4 + i];
      b2 += qv.f[8 + i]  * k1.f[8 + i];
      b3 += qv.f[12 + i] * k1.f[12 + i];
    }
    const float sa = ((a0 + a1) + (a2 + a3)) * 0.25f;   // 1/sqrt(16)
    const float sb = ((b0 + b1) + (b2 + b3)) * 0.25f;
    const float mn = fmaxf(m, fmaxf(sa, sb));
    const float f  = expf(m - mn);
    const float wa = expf(sa - mn);
    const float wb = expf(sb - mn);
    z = z * f + wa + wb;
    #pragma unroll
    for (int i = 0; i < 16; i++)
      acc[i] = acc[i] * f + wa * v0.f[i] + wb * v1.f[i];
    m = mn;
  }
  const int p = (bh * 512 + qrow) * 4 + ksp;
  pm[p] = m; pz[p] = z;
  float4* pp = (float4*)&pacc[(size_t)p * 16];
  F16U ov;
  #pragma unroll
  for (int i = 0; i < 16; i++) ov.f[i] = acc[i];
  #pragma unroll
  for (int i = 0; i < 4; i++) pp[i] = ov.v4[i];
}

// merge the 4 key-splits (exact log-sum-exp) -> ob[n][128]
__global__ void k_amerge(const float* __restrict__ pm, const float* __restrict__ pz,
                         const float* __restrict__ pacc, float* __restrict__ ob) {
  const int idx = blockIdx.x * 256 + threadIdx.x;   // 0..32767
  if (idx >= 32768) return;
  const int bh = idx >> 9, qrow = idx & 511;
  const int b = bh >> 3, hh = bh & 7;
  const float m0 = pm[idx*4+0], m1 = pm[idx*4+1], m2 = pm[idx*4+2], m3 = pm[idx*4+3];
  const float ms = fmaxf(fmaxf(m0, m1), fmaxf(m2, m3));
  const float w0 = expf(m0 - ms), w1 = expf(m1 - ms);
  const float w2 = expf(m2 - ms), w3 = expf(m3 - ms);
  const float z = pz[idx*4+0]*w0 + pz[idx*4+1]*w1 + pz[idx*4+2]*w2 + pz[idx*4+3]*w3;
  const float inv = 1.f / z;
  const float* a0 = &pacc[(size_t)(idx*4+0) * 16];
  const float* a1 = &pacc[(size_t)(idx*4+1) * 16];
  const float* a2 = &pacc[(size_t)(idx*4+2) * 16];
  const float* a3 = &pacc[(size_t)(idx*4+3) * 16];
  float* op = &ob[(size_t)(b * 512 + qrow) * 128 + hh * 16];
  #pragma unroll
  for (int d = 0; d < 16; d++)
    op[d] = (a0[d]*w0 + a1[d]*w1 + a2[d]*w2 + a3[d]*w3) * inv;
}

// out[N x 3] = y2[N x 64] @ w3 + b3 -- OUTPUT IS FLOAT32
__global__ void k_final(const float* __restrict__ y2, const float* __restrict__ w3,
                        const float* __restrict__ b3, float* __restrict__ out) {
  const int idx = blockIdx.x * 256 + threadIdx.x;
  if (idx >= NN * 3) return;
  const int n = idx / 3, j = idx % 3;
  float s = b3[j];
  const float* yp = y2 + (size_t)n * 64;
  #pragma unroll
  for (int c = 0; c < 64; c++) s += yp[c] * w3[c * 3 + j];
  out[idx] = s;
}

extern "C" void kernel_launch(void* const* d_in, const int* in_sizes, int n_in,
                              void* d_out, int out_size, void* d_ws, size_t ws_size,
                              hipStream_t stream) {
  const int*   x         = (const int*)d_in[0];
  const int*   eidx      = (const int*)d_in[1];
  const float* edge_attr = (const float*)d_in[2];
  const float* atom_emb  = (const float*)d_in[4];
  const float* edge_w    = (const float*)d_in[5];
  const float* edge_b    = (const float*)d_in[6];
  const float* wq        = (const float*)d_in[7];
  const float* bq        = (const float*)d_in[8];
  const float* wk        = (const float*)d_in[9];
  const float* bk        = (const float*)d_in[10];
  const float* wv        = (const float*)d_in[11];
  const float* bv        = (const float*)d_in[12];
  const float* we        = (const float*)d_in[13];
  const float* wskip     = (const float*)d_in[14];
  const float* bskip     = (const float*)d_in[15];
  const float* ln_g      = (const float*)d_in[16];
  const float* ln_b      = (const float*)d_in[17];
  const float* mha_in_w  = (const float*)d_in[18];
  const float* mha_in_b  = (const float*)d_in[19];
  const float* mha_out_w = (const float*)d_in[20];
  const float* mha_out_b = (const float*)d_in[21];
  const float* w1        = (const float*)d_in[22];
  const float* b1        = (const float*)d_in[23];
  const float* w2        = (const float*)d_in[24];
  const float* b2        = (const float*)d_in[25];
  const float* w3        = (const float*)d_in[26];
  const float* b3        = (const float*)d_in[27];

  float* ws   = (float*)d_ws;
  float* h    = ws;
  float* ef   = h + 524288;
  float* qb   = ef + 524288;
  float* kb   = qb + 4194304;
  float* vb   = kb + 4194304;
  float* qe   = vb + 4194304;
  float* big  = qe + 1048576;       // 4194304, subdivided:
  float* accm = big;                //   524288
  float* corrb= big + 524288;       //   524288
  float* skb  = big + 1048576;      //   524288
  float* sbuf = big + 4194304;      // 1048576
  // MHA-phase aliases (layer q/k/v buffers dead by then)
  float* qkvm = qb;                 // N*384
  float* kt   = vb;                 // 524288
  float* vt   = vb + 524288;        // 524288
  float* pm   = vb + 1048576;       // 131072
  float* pz   = vb + 1179648;       // 131072
  float* pacc = vb + 1310720;       // 2097152
  float* ob   = kb;
  float* mo   = kb + 524288;
  float* y1   = kb + 1048576;
  float* y2   = kb + 1572864;
  int* counts = (int*)(sbuf + 1048576);
  int* offs   = counts + 4100;
  int* heads  = offs + 4100;
  int* elist  = heads + 4100;

  k_init<<<2048, 256, 0, stream>>>(x, atom_emb, edge_attr, edge_w, edge_b, h, ef, counts);
  k_hist<<<64, 256, 0, stream>>>(eidx, counts);
  k_scan<<<1, 1024, 0, stream>>>(counts, offs, heads);
  k_scatter<<<64, 256, 0, stream>>>(eidx, heads, elist);

  for (int i = 0; i < NLAYERS; i++) {
    const float* wq_i  = wq + (size_t)i * 131072;
    const float* wk_i  = wk + (size_t)i * 131072;
    const float* wv_i  = wv + (size_t)i * 131072;
    const float* bq_i  = bq + (size_t)i * 1024;
    const float* bk_i  = bk + (size_t)i * 1024;
    const float* bv_i  = bv + (size_t)i * 1024;
    const float* we_i  = we + (size_t)i * 32768;
    const float* wsk_i = wskip + (size_t)i * 16384;
    const float* bsk_i = bskip + (size_t)i * 128;
    const float* g_i   = ln_g + (size_t)i * 128;
    const float* b_i   = ln_b + (size_t)i * 128;

    k_gemmqkv<<<dim3(16, 64, 4), 256, 0, stream>>>(h, wq_i, wk_i, wv_i, wsk_i,
                                                   bq_i, bk_i, bv_i, bsk_i,
                                                   qb, kb, vb, skb);
    k_qe<<<512, 256, 0, stream>>>(qb, we_i, qe);
    k_edge<<<4096, 64, 0, stream>>>(qb, kb, vb, qe, ef, offs, elist, eidx, accm, sbuf);
    k_corr<<<dim3(2, 128), 256, 0, stream>>>(sbuf, we_i, corrb);
    k_post2<<<4096, 128, 0, stream>>>(h, accm, corrb, skb, g_i, b_i);
  }

  k_gemm2<<<dim3(6, 64), 256, 0, stream>>>(h, mha_in_w, mha_in_b, qkvm, 384, 0);
  k_qkvt<<<2048, 256, 0, stream>>>(qkvm, kt, vt);
  k_attn2b<<<dim3(4, 2, 64), 256, 0, stream>>>(qkvm, kt, vt, pm, pz, pacc);
  k_amerge<<<128, 256, 0, stream>>>(pm, pz, pacc, ob);
  k_gemm2<<<dim3(2, 64), 256, 0, stream>>>(ob, mha_out_w, mha_out_b, mo, 128, 0);
  k_gemm2<<<dim3(2, 64), 256, 0, stream>>>(mo, w1, b1, y1, 128, 1);
  k_gemm2<<<dim3(1, 64), 256, 0, stream>>>(y1, w2, b2, y2, 64, 1);
  k_final<<<48, 256, 0, stream>>>(y2, w3, b3, (float*)d_out);
}

// Round 17
// 581.575 us; speedup vs baseline: 2.8300x; 1.2643x over previous
//
#include <hip/hip_runtime.h>
#include <hip/hip_bf16.h>
#include <math.h>

#define NN 4096
#define NE 16384
#define NLAYERS 4

typedef __attribute__((ext_vector_type(8))) short bf16x8;
typedef __attribute__((ext_vector_type(4))) float floatx4;

__device__ __forceinline__ float gelu_f(float x) {
  return 0.5f * x * (1.0f + erff(x * 0.70710678118654752440f));
}

// split f32 into hi+lo bf16 (hi = RN(a), lo = RN(a - hi)); hi+lo accurate to ~2^-17
__device__ __forceinline__ void bsplit(float a, unsigned short& hi, unsigned short& lo) {
  __hip_bfloat16 h16 = __float2bfloat16(a);
  hi = *(unsigned short*)&h16;
  const float r = a - __bfloat162float(h16);
  __hip_bfloat16 l16 = __float2bfloat16(r);
  lo = *(unsigned short*)&l16;
}

union F16U { float4 v4[4]; float f[16]; };

__global__ void k_init(const int* __restrict__ x, const float* __restrict__ atom_emb,
                       const float* __restrict__ edge_attr, const float* __restrict__ edge_w,
                       const float* __restrict__ edge_b, float* __restrict__ h,
                       float* __restrict__ ef, int* __restrict__ counts) {
  const int idx = blockIdx.x * 256 + threadIdx.x;      // 0..524287 (= NN*128 = NE*32)
  h[idx] = atom_emb[x[idx >> 7] * 128 + (idx & 127)];
  ef[idx] = edge_attr[idx >> 5] * edge_w[idx & 31] + edge_b[idx & 31];
  if (idx < NN) counts[idx] = 0;
}

__global__ void k_hist(const int* __restrict__ eidx, int* __restrict__ counts) {
  const int e = blockIdx.x * 256 + threadIdx.x;
  if (e < NE) atomicAdd(&counts[eidx[NE + e]], 1);
}

__global__ void k_scan(const int* __restrict__ counts, int* __restrict__ offs,
                       int* __restrict__ heads) {
  __shared__ int tmp[1024];
  const int t = threadIdx.x;
  const int c0 = counts[t*4], c1 = counts[t*4+1], c2 = counts[t*4+2], c3 = counts[t*4+3];
  const int s = c0 + c1 + c2 + c3;
  tmp[t] = s; __syncthreads();
  for (int off = 1; off < 1024; off <<= 1) {
    int v = (t >= off) ? tmp[t - off] : 0;
    __syncthreads();
    tmp[t] += v;
    __syncthreads();
  }
  int base = tmp[t] - s;
  offs[t*4]   = base;                heads[t*4]   = base;
  offs[t*4+1] = base + c0;           heads[t*4+1] = base + c0;
  offs[t*4+2] = base + c0 + c1;      heads[t*4+2] = base + c0 + c1;
  offs[t*4+3] = base + c0 + c1 + c2; heads[t*4+3] = base + c0 + c1 + c2;
  if (t == 1023) offs[NN] = tmp[1023];
}

__global__ void k_scatter(const int* __restrict__ eidx, int* __restrict__ heads,
                          int* __restrict__ elist) {
  const int e = blockIdx.x * 256 + threadIdx.x;
  if (e < NE) {
    int p = atomicAdd(&heads[eidx[NE + e]], 1);
    elist[p] = e;
  }
}

// one-time: split + transpose all layer weights -> wthi/wtlo[n][k] bf16
// per-layer short layout: [wq_t 131072 | wk_t 131072 | wv_t 131072 | wsk_t 16384]
__global__ __launch_bounds__(256) void k_wcvt(
    const float* __restrict__ wq, const float* __restrict__ wk,
    const float* __restrict__ wv, const float* __restrict__ wsk,
    unsigned short* __restrict__ wthi, unsigned short* __restrict__ wtlo) {
  const int z = blockIdx.z;            // layer*4 + mat
  const int layer = z >> 2, mat = z & 3;
  int NC; const float* W; int woff;
  if (mat == 0)      { NC = 1024; W = wq  + (size_t)layer * 131072; woff = 0; }
  else if (mat == 1) { NC = 1024; W = wk  + (size_t)layer * 131072; woff = 131072; }
  else if (mat == 2) { NC = 1024; W = wv  + (size_t)layer * 131072; woff = 262144; }
  else               { NC = 128;  W = wsk + (size_t)layer * 16384;  woff = 393216; }
  const int c0 = blockIdx.x * 64;
  if (c0 >= NC) return;
  const int k0 = blockIdx.y * 64;
  __shared__ unsigned short th[64][65], tl[64][65];
  const int t = threadIdx.x;
  for (int i = t; i < 4096; i += 256) {
    const int kk = i >> 6, c = i & 63;
    bsplit(W[(size_t)(k0 + kk) * NC + c0 + c], th[kk][c], tl[kk][c]);
  }
  __syncthreads();
  unsigned short* oh = wthi + (size_t)layer * 409600 + woff;
  unsigned short* ol = wtlo + (size_t)layer * 409600 + woff;
  for (int i = t; i < 4096; i += 256) {
    const int n = i >> 6, k = i & 63;
    oh[(size_t)(c0 + n) * 128 + k0 + k] = th[k][n];
    ol[(size_t)(c0 + n) * 128 + k0 + k] = tl[k][n];
  }
}

// per-layer: split h -> hhi/hlo bf16
__global__ void k_hcvt(const float* __restrict__ h, unsigned short* __restrict__ hhi,
                       unsigned short* __restrict__ hlo) {
  const int idx = blockIdx.x * 256 + threadIdx.x;
  bsplit(h[idx], hhi[idx], hlo[idx]);
}

// fused q/k/v/skip GEMM via split-bf16 MFMA (3 passes: hi*hi + hi*lo + lo*hi).
// 64x64 macro-tile, 4 waves; per wave: 16-row strip x 4 col-tiles, K=128 in 4 chunks.
// Frag layouts (verified m89/m91/m120): A[m=lane&15][k=quad*8+j]; B from Wt[n][k]
// symmetric; C/D col=lane&15, row=quad*4+reg.
__global__ __launch_bounds__(256) void k_mfqkv(
    const unsigned short* __restrict__ hhi, const unsigned short* __restrict__ hlo,
    const unsigned short* __restrict__ wth, const unsigned short* __restrict__ wtl,
    const float* __restrict__ bq, const float* __restrict__ bk,
    const float* __restrict__ bv, const float* __restrict__ bsk,
    float* __restrict__ qb, float* __restrict__ kb,
    float* __restrict__ vb, float* __restrict__ skb) {
  const int z = blockIdx.z;
  int NC; const float* bias; float* C; int woff;
  if (z == 0)      { NC = 1024; bias = bq;  C = qb;  woff = 0; }
  else if (z == 1) { NC = 1024; bias = bk;  C = kb;  woff = 131072; }
  else if (z == 2) { NC = 1024; bias = bv;  C = vb;  woff = 262144; }
  else             { NC = 128;  bias = bsk; C = skb; woff = 393216; }
  const int c0 = blockIdx.x * 64;
  if (c0 >= NC) return;
  __shared__ unsigned short Ah[64][136], Al[64][136], Wh[64][136], Wl[64][136];
  const int t = threadIdx.x;
  const int n0 = blockIdx.y * 64;
  for (int i = t; i < 1024; i += 256) {
    const int r = i >> 4, c8 = (i & 15) << 3;
    *(uint4*)&Ah[r][c8] = *(const uint4*)&hhi[(size_t)(n0 + r) * 128 + c8];
    *(uint4*)&Al[r][c8] = *(const uint4*)&hlo[(size_t)(n0 + r) * 128 + c8];
    *(uint4*)&Wh[r][c8] = *(const uint4*)&wth[woff + (size_t)(c0 + r) * 128 + c8];
    *(uint4*)&Wl[r][c8] = *(const uint4*)&wtl[woff + (size_t)(c0 + r) * 128 + c8];
  }
  __syncthreads();
  const int w = t >> 6, l = t & 63;
  const int quad = l >> 4, lm = l & 15;
  floatx4 acc[4] = {{0.f,0.f,0.f,0.f},{0.f,0.f,0.f,0.f},{0.f,0.f,0.f,0.f},{0.f,0.f,0.f,0.f}};
  #pragma unroll
  for (int kc = 0; kc < 4; kc++) {
    const int ko = kc * 32 + quad * 8;
    const bf16x8 ah = *(const bf16x8*)&Ah[w * 16 + lm][ko];
    const bf16x8 al = *(const bf16x8*)&Al[w * 16 + lm][ko];
    #pragma unroll
    for (int ct = 0; ct < 4; ct++) {
      const bf16x8 bh = *(const bf16x8*)&Wh[ct * 16 + lm][ko];
      const bf16x8 bl = *(const bf16x8*)&Wl[ct * 16 + lm][ko];
      acc[ct] = __builtin_amdgcn_mfma_f32_16x16x32_bf16(ah, bh, acc[ct], 0, 0, 0);
      acc[ct] = __builtin_amdgcn_mfma_f32_16x16x32_bf16(ah, bl, acc[ct], 0, 0, 0);
      acc[ct] = __builtin_amdgcn_mfma_f32_16x16x32_bf16(al, bh, acc[ct], 0, 0, 0);
    }
  }
  #pragma unroll
  for (int ct = 0; ct < 4; ct++) {
    const int col = c0 + ct * 16 + lm;
    const float bb = bias[col];
    #pragma unroll
    for (int r = 0; r < 4; r++) {
      const int row = n0 + w * 16 + quad * 4 + r;
      C[(size_t)row * NC + col] = acc[ct][r] + bb;
    }
  }
}

// generic f32 GEMM (MHA-phase): C[N x NC] = act(A[N x 128] @ W[128 x NC] + bias)
__global__ __launch_bounds__(256) void k_gemm2(const float* __restrict__ A,
                                               const float* __restrict__ W,
                                               const float* __restrict__ bias,
                                               float* __restrict__ C, int NC, int gelu) {
  __shared__ float As[128][65];
  __shared__ float Ws[128][64];
  const int t = threadIdx.x;
  const int n0 = blockIdx.y * 64, c0 = blockIdx.x * 64;
  for (int i = t; i < 2048; i += 256) {
    const int r = i & 63, k4 = (i >> 6) << 2;
    const float4 a = *(const float4*)&A[(size_t)(n0 + r) * 128 + k4];
    As[k4+0][r] = a.x; As[k4+1][r] = a.y; As[k4+2][r] = a.z; As[k4+3][r] = a.w;
  }
  for (int i = t; i < 2048; i += 256) {
    const int kk = i >> 4, c4 = (i & 15) << 2;
    *(float4*)&Ws[kk][c4] = *(const float4*)&W[(size_t)kk * NC + c0 + c4];
  }
  __syncthreads();
  const int tr = (t >> 4) << 2;
  const int tc = (t & 15) << 2;
  float acc[4][4];
  #pragma unroll
  for (int i = 0; i < 4; i++)
    #pragma unroll
    for (int j = 0; j < 4; j++) acc[i][j] = 0.f;
  #pragma unroll 8
  for (int k = 0; k < 128; k++) {
    const float4 av = *(const float4*)&As[k][tr];
    const float4 wv = *(const float4*)&Ws[k][tc];
    acc[0][0] += av.x*wv.x; acc[0][1] += av.x*wv.y; acc[0][2] += av.x*wv.z; acc[0][3] += av.x*wv.w;
    acc[1][0] += av.y*wv.x; acc[1][1] += av.y*wv.y; acc[1][2] += av.y*wv.z; acc[1][3] += av.y*wv.w;
    acc[2][0] += av.z*wv.x; acc[2][1] += av.z*wv.y; acc[2][2] += av.z*wv.z; acc[2][3] += av.z*wv.w;
    acc[3][0] += av.w*wv.x; acc[3][1] += av.w*wv.y; acc[3][2] += av.w*wv.z; acc[3][3] += av.w*wv.w;
  }
  const float4 bb = *(const float4*)&bias[c0 + tc];
  #pragma unroll
  for (int i = 0; i < 4; i++) {
    float4 v;
    v.x = acc[i][0] + bb.x; v.y = acc[i][1] + bb.y;
    v.z = acc[i][2] + bb.z; v.w = acc[i][3] + bb.w;
    if (gelu) { v.x = gelu_f(v.x); v.y = gelu_f(v.y); v.z = gelu_f(v.z); v.w = gelu_f(v.w); }
    *(float4*)&C[(size_t)(n0 + tr + i) * NC + c0 + tc] = v;
  }
}

// corr[n][d] = sum_{k<256} sbuf[n][k] * we[(k&31)*1024 + (k>>5)*128 + d]
__global__ __launch_bounds__(256) void k_corr(const float* __restrict__ sbuf,
                                              const float* __restrict__ we_l,
                                              float* __restrict__ corrb) {
  __shared__ float As[32][256];
  __shared__ float Ws[128][64];
  const int t = threadIdx.x;
  const int n0 = blockIdx.y * 32, c0 = blockIdx.x * 64;
  for (int i = t; i < 2048; i += 256) {
    const int r = i >> 6, c4 = (i & 63) << 2;
    *(float4*)&As[r][c4] = *(const float4*)&sbuf[(size_t)(n0 + r) * 256 + c4];
  }
  const int tx = t & 63, ty = t >> 6;
  float acc[8] = {0.f,0.f,0.f,0.f,0.f,0.f,0.f,0.f};
  for (int kc = 0; kc < 2; kc++) {
    __syncthreads();
    for (int i = t; i < 2048; i += 256) {
      const int kk = i >> 4, c4 = (i & 15) << 2;
      const int k = kc * 128 + kk;
      const int hh = k >> 5, c = k & 31;
      *(float4*)&Ws[kk][c4] = *(const float4*)&we_l[(size_t)c * 1024 + hh * 128 + c0 + c4];
    }
    __syncthreads();
    for (int kk = 0; kk < 128; kk += 4) {
      const float w0 = Ws[kk+0][tx];
      const float w1 = Ws[kk+1][tx];
      const float w2 = Ws[kk+2][tx];
      const float w3 = Ws[kk+3][tx];
      #pragma unroll
      for (int j = 0; j < 8; j++) {
        const float4 a = *(const float4*)&As[ty*8 + j][kc*128 + kk];
        acc[j] += a.x*w0 + a.y*w1 + a.z*w2 + a.w*w3;
      }
    }
  }
  #pragma unroll
  for (int j = 0; j < 8; j++)
    corrb[(size_t)(n0 + ty*8 + j) * 128 + c0 + tx] = acc[j];
}

// qe[n,h,c] = sum_d q[n,h*128+d] * we[c,h*128+d]; 8 nodes per block
__global__ __launch_bounds__(256) void k_qe(const float* __restrict__ q,
                                            const float* __restrict__ we_l,
                                            float* __restrict__ qe) {
  __shared__ float qs[8][1024];
  const int t = threadIdx.x;
  const int n0 = blockIdx.x * 8;
  for (int i = t; i < 2048; i += 256) {
    const int nn = i >> 8, c4 = (i & 255) << 2;
    *(float4*)&qs[nn][c4] = *(const float4*)&q[(size_t)(n0 + nn) * 1024 + c4];
  }
  __syncthreads();
  const int hh = t >> 5, c = t & 31;
  const float* wp = we_l + (size_t)c * 1024 + hh * 128;
  float acc[8] = {0.f,0.f,0.f,0.f,0.f,0.f,0.f,0.f};
  for (int d8 = 0; d8 < 16; d8++) {
    const float4 wa = *(const float4*)&wp[d8 * 8];
    const float4 wb = *(const float4*)&wp[d8 * 8 + 4];
    #pragma unroll
    for (int nn = 0; nn < 8; nn++) {
      const float4 a0 = *(const float4*)&qs[nn][hh*128 + d8*8];
      const float4 a1 = *(const float4*)&qs[nn][hh*128 + d8*8 + 4];
      acc[nn] += a0.x*wa.x + a0.y*wa.y + a0.z*wa.z + a0.w*wa.w
               + a1.x*wb.x + a1.y*wb.y + a1.z*wb.z + a1.w*wb.w;
    }
  }
  #pragma unroll
  for (int nn = 0; nn < 8; nn++)
    qe[(size_t)(n0 + nn) * 256 + hh * 32 + c] = acc[nn];
}

// per-dst-node edge attention with online softmax; 1 wave per node.
__global__ __launch_bounds__(64) void k_edge(const float* __restrict__ qb,
                                             const float* __restrict__ kb,
                                             const float* __restrict__ vb,
                                             const float* __restrict__ qe,
                                             const float* __restrict__ ef,
                                             const int* __restrict__ offs,
                                             const int* __restrict__ elist,
                                             const int* __restrict__ eidx,
                                             float* __restrict__ accm,
                                             float* __restrict__ sbuf) {
  const int n = blockIdx.x;
  const int lane = threadIdx.x;
  const int hh = lane >> 3, s8 = lane & 7;
  const int d0 = hh * 128 + s8 * 16;
  F16U qv;
  {
    const float4* qp = (const float4*)(qb + (size_t)n * 1024 + d0);
    #pragma unroll
    for (int i = 0; i < 4; i++) qv.v4[i] = qp[i];
  }
  const float4 qe4 = *(const float4*)(qe + (size_t)n * 256 + hh * 32 + s8 * 4);
  float m = -INFINITY, z = 0.f;
  float acc[16];
  #pragma unroll
  for (int i = 0; i < 16; i++) acc[i] = 0.f;
  float sx = 0.f, sy = 0.f, sz = 0.f, sw = 0.f;
  const int e0 = offs[n], e1 = offs[n + 1];
  for (int tt = e0; tt < e1; tt++) {
    const int e = elist[tt];
    const int src = eidx[e];
    F16U kv;
    {
      const float4* kp = (const float4*)(kb + (size_t)src * 1024 + d0);
      #pragma unroll
      for (int i = 0; i < 4; i++) kv.v4[i] = kp[i];
    }
    const float4 ef4 = *(const float4*)(ef + (size_t)e * 32 + s8 * 4);
    float p0 = qe4.x*ef4.x + qe4.y*ef4.y;
    float p1 = qe4.z*ef4.z + qe4.w*ef4.w;
    float p2 = 0.f, p3 = 0.f;
    #pragma unroll
    for (int i = 0; i < 4; i++) {
      p0 += qv.f[i]      * kv.f[i];
      p1 += qv.f[4 + i]  * kv.f[4 + i];
      p2 += qv.f[8 + i]  * kv.f[8 + i];
      p3 += qv.f[12 + i] * kv.f[12 + i];
    }
    float p = (p0 + p1) + (p2 + p3);
    p += __shfl_xor(p, 1);
    p += __shfl_xor(p, 2);
    p += __shfl_xor(p, 4);
    const float logit = p * 0.08838834764831845f;   // 1/sqrt(128)
    const float mn = fmaxf(m, logit);
    const float f = expf(m - mn);
    const float w = expf(logit - mn);
    z = z * f + w;
    F16U vv;
    {
      const float4* vp = (const float4*)(vb + (size_t)src * 1024 + d0);
      #pragma unroll
      for (int i = 0; i < 4; i++) vv.v4[i] = vp[i];
    }
    #pragma unroll
    for (int i = 0; i < 16; i++) acc[i] = acc[i] * f + w * vv.f[i];
    sx = sx * f + w * ef4.x; sy = sy * f + w * ef4.y;
    sz = sz * f + w * ef4.z; sw = sw * f + w * ef4.w;
    m = mn;
  }
  const float inv = 1.f / (z + 1e-16f);
  *(float4*)(sbuf + (size_t)n * 256 + hh * 32 + s8 * 4) =
      make_float4(sx * inv, sy * inv, sz * inv, sw * inv);
  F16U ov;
  #pragma unroll
  for (int i = 0; i < 16; i++) ov.f[i] = acc[i] * inv;
  #pragma unroll
  for (int mask = 8; mask <= 32; mask <<= 1)
    #pragma unroll
    for (int i = 0; i < 16; i++) ov.f[i] += __shfl_xor(ov.f[i], mask);
  if (hh == 0) {
    #pragma unroll
    for (int i = 0; i < 16; i++) ov.f[i] *= 0.125f;
    float4* ap = (float4*)(accm + (size_t)n * 128 + s8 * 16);
    #pragma unroll
    for (int i = 0; i < 4; i++) ap[i] = ov.v4[i];
  }
}

// out = LN(accm + 0.125*corr + skb + h) * g + b, then gelu; in-place on h.
__global__ __launch_bounds__(128) void k_post2(float* __restrict__ h,
                                               const float* __restrict__ accm,
                                               const float* __restrict__ corrb,
                                               const float* __restrict__ skb,
                                               const float* __restrict__ lng,
                                               const float* __restrict__ lnb) {
  const int n = blockIdx.x, d = threadIdx.x;
  __shared__ float red[128], stat[2];
  const size_t o = (size_t)n * 128 + d;
  const float out = accm[o] + 0.125f * corrb[o] + skb[o] + h[o];
  red[d] = out; __syncthreads();
  for (int s2 = 64; s2 > 0; s2 >>= 1) { if (d < s2) red[d] += red[d + s2]; __syncthreads(); }
  if (d == 0) stat[0] = red[0] * (1.f / 128.f);
  __syncthreads();
  const float mean = stat[0];
  const float dev = out - mean;
  red[d] = dev * dev; __syncthreads();
  for (int s2 = 64; s2 > 0; s2 >>= 1) { if (d < s2) red[d] += red[d + s2]; __syncthreads(); }
  if (d == 0) stat[1] = red[0] * (1.f / 128.f);
  __syncthreads();
  const float var = stat[1];
  const float y = dev / sqrtf(var + 1e-5f) * lng[d] + lnb[d];
  h[o] = gelu_f(y);
}

// transpose k/v out of qkvm into [bh][512][16] contiguous
__global__ void k_qkvt(const float* __restrict__ qkvm, float* __restrict__ kt,
                       float* __restrict__ vt) {
  const int idx = blockIdx.x * 256 + threadIdx.x;   // 0..524287
  const int bh = idx >> 13, rest = idx & 8191;
  const int j = rest >> 4, d = rest & 15;
  const int b = bh >> 3, hh = bh & 7;
  const size_t src = (size_t)(b * 512 + j) * 384 + hh * 16 + d;
  kt[idx] = qkvm[src + 128];
  vt[idx] = qkvm[src + 256];
}

// flash-split dense MHA: grid (ks=4, qt=2, bh=64), 256 thr, 16 KB LDS.
__global__ __launch_bounds__(256) void k_attn2b(const float* __restrict__ qkvm,
                                                const float* __restrict__ kt,
                                                const float* __restrict__ vt,
                                                float* __restrict__ pm,
                                                float* __restrict__ pz,
                                                float* __restrict__ pacc) {
  __shared__ float ks2[128][16];
  __shared__ float vs2[128][16];
  const int ksp = blockIdx.x, qt = blockIdx.y, bh = blockIdx.z;
  const int b = bh >> 3, hh = bh & 7;
  const int t = threadIdx.x;
  const size_t kbase = ((size_t)bh * 512 + ksp * 128) * 16;
  for (int i = t; i < 512; i += 256) {
    const int j = i >> 2, d4 = (i & 3) << 2;
    *(float4*)&ks2[j][d4] = *(const float4*)&kt[kbase + (size_t)j * 16 + d4];
    *(float4*)&vs2[j][d4] = *(const float4*)&vt[kbase + (size_t)j * 16 + d4];
  }
  __syncthreads();
  const int qrow = qt * 256 + t;
  const int nq = b * 512 + qrow;
  F16U qv;
  {
    const float4* qp = (const float4*)(qkvm + (size_t)nq * 384 + hh * 16);
    #pragma unroll
    for (int i = 0; i < 4; i++) qv.v4[i] = qp[i];
  }
  float m = -INFINITY, z = 0.f;
  float acc[16];
  #pragma unroll
  for (int i = 0; i < 16; i++) acc[i] = 0.f;
  for (int j = 0; j < 128; j += 2) {
    F16U k0, k1, v0, v1;
    {
      const float4* p0 = (const float4*)ks2[j];
      const float4* p1 = (const float4*)ks2[j + 1];
      const float4* q0 = (const float4*)vs2[j];
      const float4* q1 = (const float4*)vs2[j + 1];
      #pragma unroll
      for (int i = 0; i < 4; i++) {
        k0.v4[i] = p0[i]; k1.v4[i] = p1[i];
        v0.v4[i] = q0[i]; v1.v4[i] = q1[i];
      }
    }
    float a0 = 0.f, a1 = 0.f, a2 = 0.f, a3 = 0.f;
    float b0 = 0.f, b1 = 0.f, b2 = 0.f, b3 = 0.f;
    #pragma unroll
    for (int i = 0; i < 4; i++) {
      a0 += qv.f[i]      * k0.f[i];
      a1 += qv.f[4 + i]  * k0.f[4 + i];
      a2 += qv.f[8 + i]  * k0.f[8 + i];
      a3 += qv.f[12 + i] * k0.f[12 + i];
      b0 += qv.f[i]      * k1.f[i];
      b1 += qv.f[4 + i]  * k1.f[4 + i];
      b2 += qv.f[8 + i]  * k1.f[8 + i];
      b3 += qv.f[12 + i] * k1.f[12 + i];
    }
    const float sa = ((a0 + a1) + (a2 + a3)) * 0.25f;   // 1/sqrt(16)
    const float sb = ((b0 + b1) + (b2 + b3)) * 0.25f;
    const float mn = fmaxf(m, fmaxf(sa, sb));
    const float f  = expf(m - mn);
    const float wa = expf(sa - mn);
    const float wb = expf(sb - mn);
    z = z * f + wa + wb;
    #pragma unroll
    for (int i = 0; i < 16; i++)
      acc[i] = acc[i] * f + wa * v0.f[i] + wb * v1.f[i];
    m = mn;
  }
  const int p = (bh * 512 + qrow) * 4 + ksp;
  pm[p] = m; pz[p] = z;
  float4* pp = (float4*)&pacc[(size_t)p * 16];
  F16U ov;
  #pragma unroll
  for (int i = 0; i < 16; i++) ov.f[i] = acc[i];
  #pragma unroll
  for (int i = 0; i < 4; i++) pp[i] = ov.v4[i];
}

// merge the 4 key-splits (exact log-sum-exp) -> ob[n][128]
__global__ void k_amerge(const float* __restrict__ pm, const float* __restrict__ pz,
                         const float* __restrict__ pacc, float* __restrict__ ob) {
  const int idx = blockIdx.x * 256 + threadIdx.x;   // 0..32767
  if (idx >= 32768) return;
  const int bh = idx >> 9, qrow = idx & 511;
  const int b = bh >> 3, hh = bh & 7;
  const float m0 = pm[idx*4+0], m1 = pm[idx*4+1], m2 = pm[idx*4+2], m3 = pm[idx*4+3];
  const float ms = fmaxf(fmaxf(m0, m1), fmaxf(m2, m3));
  const float w0 = expf(m0 - ms), w1 = expf(m1 - ms);
  const float w2 = expf(m2 - ms), w3 = expf(m3 - ms);
  const float z = pz[idx*4+0]*w0 + pz[idx*4+1]*w1 + pz[idx*4+2]*w2 + pz[idx*4+3]*w3;
  const float inv = 1.f / z;
  const float* a0 = &pacc[(size_t)(idx*4+0) * 16];
  const float* a1 = &pacc[(size_t)(idx*4+1) * 16];
  const float* a2 = &pacc[(size_t)(idx*4+2) * 16];
  const float* a3 = &pacc[(size_t)(idx*4+3) * 16];
  float* op = &ob[(size_t)(b * 512 + qrow) * 128 + hh * 16];
  #pragma unroll
  for (int d = 0; d < 16; d++)
    op[d] = (a0[d]*w0 + a1[d]*w1 + a2[d]*w2 + a3[d]*w3) * inv;
}

// out[N x 3] = y2[N x 64] @ w3 + b3 -- OUTPUT IS FLOAT32
__global__ void k_final(const float* __restrict__ y2, const float* __restrict__ w3,
                        const float* __restrict__ b3, float* __restrict__ out) {
  const int idx = blockIdx.x * 256 + threadIdx.x;
  if (idx >= NN * 3) return;
  const int n = idx / 3, j = idx % 3;
  float s = b3[j];
  const float* yp = y2 + (size_t)n * 64;
  #pragma unroll
  for (int c = 0; c < 64; c++) s += yp[c] * w3[c * 3 + j];
  out[idx] = s;
}

extern "C" void kernel_launch(void* const* d_in, const int* in_sizes, int n_in,
                              void* d_out, int out_size, void* d_ws, size_t ws_size,
                              hipStream_t stream) {
  const int*   x         = (const int*)d_in[0];
  const int*   eidx      = (const int*)d_in[1];
  const float* edge_attr = (const float*)d_in[2];
  const float* atom_emb  = (const float*)d_in[4];
  const float* edge_w    = (const float*)d_in[5];
  const float* edge_b    = (const float*)d_in[6];
  const float* wq        = (const float*)d_in[7];
  const float* bq        = (const float*)d_in[8];
  const float* wk        = (const float*)d_in[9];
  const float* bk        = (const float*)d_in[10];
  const float* wv        = (const float*)d_in[11];
  const float* bv        = (const float*)d_in[12];
  const float* we        = (const float*)d_in[13];
  const float* wskip     = (const float*)d_in[14];
  const float* bskip     = (const float*)d_in[15];
  const float* ln_g      = (const float*)d_in[16];
  const float* ln_b      = (const float*)d_in[17];
  const float* mha_in_w  = (const float*)d_in[18];
  const float* mha_in_b  = (const float*)d_in[19];
  const float* mha_out_w = (const float*)d_in[20];
  const float* mha_out_b = (const float*)d_in[21];
  const float* w1        = (const float*)d_in[22];
  const float* b1        = (const float*)d_in[23];
  const float* w2        = (const float*)d_in[24];
  const float* b2        = (const float*)d_in[25];
  const float* w3        = (const float*)d_in[26];
  const float* b3        = (const float*)d_in[27];

  float* ws   = (float*)d_ws;
  float* h    = ws;
  float* ef   = h + 524288;
  float* qb   = ef + 524288;
  float* kb   = qb + 4194304;
  float* vb   = kb + 4194304;
  float* qe   = vb + 4194304;
  float* big  = qe + 1048576;       // 4194304 floats, subdivided:
  float* accm = big;                //   524288
  float* corrb= big + 524288;       //   524288
  float* skb  = big + 1048576;      //   524288
  // split-bf16 buffers carved from the unused tail of big:
  unsigned short* hhi  = (unsigned short*)(big + 1572864);   // 524288 shorts
  unsigned short* hlo  = hhi + 524288;                       // 524288 shorts
  unsigned short* wthi = hlo + 524288;                       // 1638400 shorts
  unsigned short* wtlo = wthi + 1638400;                     // 1638400 shorts (ends < big+4194304)
  float* sbuf = big + 4194304;      // 1048576
  // MHA-phase aliases (layer q/k/v buffers dead by then)
  float* qkvm = qb;                 // N*384
  float* kt   = vb;                 // 524288
  float* vt   = vb + 524288;        // 524288
  float* pm   = vb + 1048576;       // 131072
  float* pz   = vb + 1179648;       // 131072
  float* pacc = vb + 1310720;       // 2097152
  float* ob   = kb;
  float* mo   = kb + 524288;
  float* y1   = kb + 1048576;
  float* y2   = kb + 1572864;
  int* counts = (int*)(sbuf + 1048576);
  int* offs   = counts + 4100;
  int* heads  = offs + 4100;
  int* elist  = heads + 4100;

  k_init<<<2048, 256, 0, stream>>>(x, atom_emb, edge_attr, edge_w, edge_b, h, ef, counts);
  k_hist<<<64, 256, 0, stream>>>(eidx, counts);
  k_scan<<<1, 1024, 0, stream>>>(counts, offs, heads);
  k_scatter<<<64, 256, 0, stream>>>(eidx, heads, elist);
  k_wcvt<<<dim3(16, 2, 16), 256, 0, stream>>>(wq, wk, wv, wskip, wthi, wtlo);

  for (int i = 0; i < NLAYERS; i++) {
    const float* bq_i  = bq + (size_t)i * 1024;
    const float* bk_i  = bk + (size_t)i * 1024;
    const float* bv_i  = bv + (size_t)i * 1024;
    const float* we_i  = we + (size_t)i * 32768;
    const float* bsk_i = bskip + (size_t)i * 128;
    const float* g_i   = ln_g + (size_t)i * 128;
    const float* b_i   = ln_b + (size_t)i * 128;
    const unsigned short* wth_i = wthi + (size_t)i * 409600;
    const unsigned short* wtl_i = wtlo + (size_t)i * 409600;

    k_hcvt<<<2048, 256, 0, stream>>>(h, hhi, hlo);
    k_mfqkv<<<dim3(16, 64, 4), 256, 0, stream>>>(hhi, hlo, wth_i, wtl_i,
                                                 bq_i, bk_i, bv_i, bsk_i,
                                                 qb, kb, vb, skb);
    k_qe<<<512, 256, 0, stream>>>(qb, we_i, qe);
    k_edge<<<4096, 64, 0, stream>>>(qb, kb, vb, qe, ef, offs, elist, eidx, accm, sbuf);
    k_corr<<<dim3(2, 128), 256, 0, stream>>>(sbuf, we_i, corrb);
    k_post2<<<4096, 128, 0, stream>>>(h, accm, corrb, skb, g_i, b_i);
  }

  k_gemm2<<<dim3(6, 64), 256, 0, stream>>>(h, mha_in_w, mha_in_b, qkvm, 384, 0);
  k_qkvt<<<2048, 256, 0, stream>>>(qkvm, kt, vt);
  k_attn2b<<<dim3(4, 2, 64), 256, 0, stream>>>(qkvm, kt, vt, pm, pz, pacc);
  k_amerge<<<128, 256, 0, stream>>>(pm, pz, pacc, ob);
  k_gemm2<<<dim3(2, 64), 256, 0, stream>>>(ob, mha_out_w, mha_out_b, mo, 128, 0);
  k_gemm2<<<dim3(2, 64), 256, 0, stream>>>(mo, w1, b1, y1, 128, 1);
  k_gemm2<<<dim3(1, 64), 256, 0, stream>>>(y1, w2, b2, y2, 64, 1);
  k_final<<<48, 256, 0, stream>>>(y2, w3, b3, (float*)d_out);
}